// Round 14
// baseline (135.234 us; speedup 1.0000x reference)
//
#include <hip/hip_runtime.h>
#include <stdint.h>

#define B_    2
#define N_    2048
#define DIM_  1024
#define H_    16
#define DH_   64
#define NR_   4096     // B*N rows
#define NQKV_ 3072
#define NQK_  2048     // q,k columns kept in qkv2

typedef unsigned short u16;
typedef __attribute__((ext_vector_type(8))) short short8;
typedef __attribute__((ext_vector_type(4))) float f32x4;

static __device__ __forceinline__ u16 f2bf(float f){
  union { float f; uint32_t u; } x; x.f = f;
  return (u16)((x.u + 0x7fffu + ((x.u >> 16) & 1u)) >> 16);
}
static __device__ __forceinline__ float bf2f(uint32_t b){
  union { uint32_t u; float f; } x; x.u = b << 16;
  return x.f;
}
// hardware packed f32->bf16 (RNE): D = {lo: bf16(a), hi: bf16(b)}
static __device__ __forceinline__ uint32_t cvtpk(float a, float b){
  uint32_t r;
  asm("v_cvt_pk_bf16_f32 %0, %1, %2" : "=v"(r) : "v"(a), "v"(b));
  return r;
}

// global -> LDS direct copy, 16B per lane; LDS dest is wave-uniform base + lane*16
#define GLL16(gp, lp) __builtin_amdgcn_global_load_lds( \
    (const __attribute__((address_space(1))) void*)(gp), \
    (__attribute__((address_space(3))) void*)(lp), 16, 0, 0)

#define SCHEDB __builtin_amdgcn_sched_barrier(0)
#define BARRIER __builtin_amdgcn_s_barrier()

// ---------------- RMSNorm + cast to bf16 ----------------
__global__ __launch_bounds__(256) void k_rmsnorm(const float* __restrict__ x,
                                                 const float* __restrict__ w,
                                                 u16* __restrict__ xn){
  int row = blockIdx.x;
  int t = threadIdx.x;
  float4 v = ((const float4*)(x + (size_t)row * DIM_))[t];
  float ss = v.x*v.x + v.y*v.y + v.z*v.z + v.w*v.w;
#pragma unroll
  for (int m = 1; m < 64; m <<= 1) ss += __shfl_xor(ss, m, 64);
  __shared__ float red[4];
  if ((t & 63) == 0) red[t >> 6] = ss;
  __syncthreads();
  float tot = red[0] + red[1] + red[2] + red[3];
  float r = rsqrtf(tot * (1.0f / DIM_) + 1.1920929e-07f);
  float4 wv = ((const float4*)w)[t];
  union { u16 u[4]; uint2 v2; } o;
  o.u[0] = f2bf(v.x * r * wv.x);
  o.u[1] = f2bf(v.y * r * wv.y);
  o.u[2] = f2bf(v.z * r * wv.z);
  o.u[3] = f2bf(v.w * r * wv.w);
  ((uint2*)(xn + (size_t)row * DIM_))[t] = o.v2;
}

// ---------------- fp32 [R][C] -> bf16 [C][R] transpose-cast ----------------
__global__ __launch_bounds__(256) void k_tcast(const float* __restrict__ src,
                                               u16* __restrict__ dst, int R, int C){
  __shared__ float ls[64][65];
  int c0 = blockIdx.x * 64, r0 = blockIdx.y * 64;
  int t = threadIdx.x;
  int rr = t >> 2, q = t & 3;
  const float* s = src + (size_t)(r0 + rr) * C + c0 + q * 16;
#pragma unroll
  for (int j = 0; j < 4; j++){
    float4 v = ((const float4*)s)[j];
    ls[rr][q*16 + j*4 + 0] = v.x;
    ls[rr][q*16 + j*4 + 1] = v.y;
    ls[rr][q*16 + j*4 + 2] = v.z;
    ls[rr][q*16 + j*4 + 3] = v.w;
  }
  __syncthreads();
  int cc = t >> 2;
  union { u16 u[16]; uint4 v4[2]; } o;
#pragma unroll
  for (int i = 0; i < 16; i++) o.u[i] = f2bf(ls[q*16 + i][cc]);
  u16* d = dst + (size_t)(c0 + cc) * R + r0 + q * 16;
  ((uint4*)d)[0] = o.v4[0];
  ((uint4*)d)[1] = o.v4[1];
}

// ---------------- cos/sin table [N][32] ----------------
__global__ void k_cs(float2* __restrict__ cs){
  int tid = blockIdx.x * blockDim.x + threadIdx.x;
  if (tid >= N_ * 32) return;
  int n = tid >> 5, i = tid & 31;
  float inv = powf(10000.0f, -(float)(2 * i) * (1.0f / 64.0f));
  float a = (float)n * inv;
  cs[tid] = make_float2(cosf(a), sinf(a));
}

// ---------------- GEMM1: 256x192 tile, BK=64, 8-phase interleave, grid 256 ----------------
// C[4096,3072] = xn @ wqkvT^T. 512 thr = 8 waves (2m x 4n), per-wave 128x48 out.
// LDS 112KB: A k-half-split [buf][kh][256r x 32k] (16KB each), B full [buf][192n x 64k]
// (24KB each). 4 phases/K-tile, 12 MFMA each; per-wave 7 loads/K-tile (A 2+2, B 3).
// Counted waits: end-p1 vmcnt(5) (A-h1 of tile kt ready), end-p3 vmcnt(2) (B of kt+1
// ready); never 0 mid-loop. Stage issues p0:Ah0' p1:B' p2:Ah1'.
// Epilogue: cols<2048 -> fused interleaved RoPE (q scaled 0.125*log2e) -> bf16 qkv2;
// cols>=2048 -> fp32 orig_v + bf16 vT2 tiled.
__global__ __launch_bounds__(512, 2) void k_gemm1(const u16* __restrict__ A,
                                                  const u16* __restrict__ Bt,
                                                  u16* __restrict__ outb,
                                                  float* __restrict__ outf,
                                                  u16* __restrict__ vt2,
                                                  const float2* __restrict__ cs){
  __shared__ u16 As[2][2][8192];   // [buf][kh][256r x 32k], chunk-XOR swizzle (64KB)
  __shared__ u16 Bs[2][12288];     // [buf][192n x 64k], chunk-XOR swizzle (48KB)
  const int K = 1024, KT = 16;

  int xcd = blockIdx.x & 7, c = blockIdx.x >> 3;       // c in 0..31
  int m0 = ((xcd >> 1) * 4 + (c >> 3)) << 8;           // m-panel 0..15 (256 rows)
  int n0 = ((xcd & 1) * 8 + (c & 7)) * 192;            // n-panel 0..15 (192 cols)

  int t = threadIdx.x, wv = t >> 6, lane = t & 63, l15 = lane & 15, g = lane >> 4;
  int wm = wv >> 2, wn = wv & 3;                       // 2 x 4 wave grid

  const u16* Ap = A + (size_t)m0 * K;
  const u16* Bp = Bt + (size_t)n0 * K;

  // A k-half (16KB = 256 rows x 32 k): 2 gload_lds/wave. row = s>>2; logical
  // 16B-chunk = (s&3) ^ ((row>>1)&3) [involution, matched on read]
  auto STG_A = [&](u16* lds, int kt, int kh){
#pragma unroll
    for (int i = 0; i < 2; i++){
      int s = (i * 8 + wv) * 64 + lane;
      int row = s >> 2;
      int lc = (s & 3) ^ ((row >> 1) & 3);
      GLL16(Ap + (size_t)row * K + kt * 64 + kh * 32 + lc * 8, lds + (i * 8 + wv) * 512);
    }
  };
  // B full tile (24KB = 192 rows x 64 k): 3 gload_lds/wave. row n = s>>3; logical
  // chunk = (s&7) ^ (n&7)
  auto STG_B = [&](u16* lds, int kt){
#pragma unroll
    for (int i = 0; i < 3; i++){
      int s = (i * 8 + wv) * 64 + lane;
      int n = s >> 3;
      int lp = (s & 7) ^ (n & 7);
      GLL16(Bp + (size_t)n * K + kt * 64 + lp * 8, lds + (i * 8 + wv) * 512);
    }
  };

  f32x4 acc[8][3] = {};

  // prologue: tile 0 fully staged (7 loads/wave); need B_0 -> allow Ah1_0 in flight
  STG_A(&As[0][0][0], 0, 0);
  STG_B(&Bs[0][0], 0);
  STG_A(&As[0][1][0], 0, 1);
  asm volatile("s_waitcnt vmcnt(2)" ::: "memory");
  SCHEDB; BARRIER; SCHEDB;

  for (int kt = 0; kt < KT; kt++){
    int buf = kt & 1, nbuf = buf ^ 1;
    bool pre = (kt + 1 < KT);
    short8 bfrag[3];
#pragma unroll
    for (int p = 0; p < 4; p++){
      const int kk = p >> 1;            // 0,0,1,1
      const int mib = (p & 1) * 4;      // 0,4,0,4
      // ds_reads (data guaranteed by previous phase's end-wait + barrier)
      if (!(p & 1)){
#pragma unroll
        for (int ni = 0; ni < 3; ni++){
          int n = wn * 48 + ni * 16 + l15;
          bfrag[ni] = *(const short8*)(&Bs[buf][n * 64 + (((kk * 4 + g) ^ (n & 7)) << 3)]);
        }
      }
      short8 afrag[4];
#pragma unroll
      for (int mi = 0; mi < 4; mi++){
        int rr = wm * 128 + (mib + mi) * 16 + l15;
        afrag[mi] = *(const short8*)(&As[buf][kk][rr * 32 + ((g ^ ((rr >> 1) & 3)) << 3)]);
      }
      // stage issue for tile kt+1: p0:A-h0', p1:B', p2:A-h1'
      if (pre){
        if (p == 0)      STG_A(&As[nbuf][0][0], kt + 1, 0);
        else if (p == 1) STG_B(&Bs[nbuf][0], kt + 1);
        else if (p == 2) STG_A(&As[nbuf][1][0], kt + 1, 1);
      }
      SCHEDB; BARRIER;
      asm volatile("s_waitcnt lgkmcnt(0)" ::: "memory");
      SCHEDB;
      __builtin_amdgcn_s_setprio(1);
#pragma unroll
      for (int mi = 0; mi < 4; mi++)
#pragma unroll
        for (int ni = 0; ni < 3; ni++)
          acc[mib + mi][ni] = __builtin_amdgcn_mfma_f32_16x16x32_bf16(afrag[mi], bfrag[ni], acc[mib + mi][ni], 0, 0, 0);
      __builtin_amdgcn_s_setprio(0);
      // end-of-phase counted waits (guarantee next phase's ds_read data)
      if (p == 1){
        if (pre) asm volatile("s_waitcnt vmcnt(5)" ::: "memory");   // A-h1 of kt ready
        else     asm volatile("s_waitcnt vmcnt(0)" ::: "memory");
      }
      if (p == 3 && pre) asm volatile("s_waitcnt vmcnt(2)" ::: "memory");  // B of kt+1 ready
      SCHEDB; BARRIER; SCHEDB;
    }
  }

#pragma unroll
  for (int mi = 0; mi < 8; mi++){
#pragma unroll
    for (int ni = 0; ni < 3; ni++){
      int col = n0 + wn * 48 + ni * 16 + l15;
#pragma unroll
      for (int r = 0; r < 4; r++){
        int row = m0 + wm * 128 + mi * 16 + g * 4 + r;
        float val = acc[mi][ni][r];
        if (col < NQK_){
          // fused interleaved RoPE: partner element lives in adjacent lane
          int n = row & (N_ - 1);
          int dpair = (col & 63) >> 1;
          float2 cv = cs[(size_t)n * 32 + dpair];
          float partner = __shfl_xor(val, 1, 64);
          float y = (l15 & 1) ? (val * cv.x + partner * cv.y)
                              : (val * cv.x - partner * cv.y);
          if (col < DIM_) y *= 0.18033688f;   // (1/8)*log2(e): log2-domain scores
          outb[(size_t)row * NQK_ + col] = f2bf(y);
        } else {
          int hh = (col - 2 * DIM_) >> 6, d = col & 63;
          int b = row >> 11, n = row & (N_ - 1);
          outf[((size_t)((b * H_ + hh) * N_ + n) << 6) + d] = val;
          // vT2 tiled: [bh][n>>5][d][n&31]
          vt2[((size_t)((b * H_ + hh) * 64 + (n >> 5)) * 64 + d) * 32 + (n & 31)] = f2bf(val);
        }
      }
    }
  }
}

// ---------------- GEMM2: 128x128 tile, BK=64, counted-vmcnt schedule ----------------
__global__ __launch_bounds__(256, 2) void k_gemm2(const u16* __restrict__ A,
                                                  const u16* __restrict__ Bt,
                                                  float* __restrict__ outf){
  __shared__ u16 As[2][8192];
  __shared__ u16 Bs[2][8192];
  const int K = 1024, KT = 16, N = 1024;

  int xcd = blockIdx.x & 7, c = blockIdx.x >> 3;       // c in 0..31
  int m0 = (xcd * 4 + (c >> 3)) << 7;
  int n0 = (c & 7) << 7;

  int t = threadIdx.x, wv = t >> 6, lane = t & 63, l15 = lane & 15, g = lane >> 4;
  int wm = wv >> 1, wn = wv & 1;

  auto STAGE = [&](int buf, int kt){
    int k0 = kt << 6;
#pragma unroll
    for (int i = 0; i < 4; i++){
      int cc = (i * 4 + wv) * 64 + lane;
      int m = cc >> 3, pos = cc & 7;
      GLL16(A + (size_t)(m0 + m) * K + k0 + ((pos ^ (m & 7)) << 3), &As[buf][(i * 4 + wv) * 512]);
    }
#pragma unroll
    for (int i = 0; i < 4; i++){
      int cc = (i * 4 + wv) * 64 + lane;
      int n = cc >> 3, pos = cc & 7;
      GLL16(Bt + (size_t)(n0 + n) * K + k0 + ((pos ^ (n & 7)) << 3), &Bs[buf][(i * 4 + wv) * 512]);
    }
  };

  f32x4 acc[4][4] = {};
  STAGE(0, 0);
  STAGE(1, 1);

  for (int kt = 0; kt < KT; kt++){
    if (kt < KT - 1) asm volatile("s_waitcnt vmcnt(8)" ::: "memory");
    else             asm volatile("s_waitcnt vmcnt(0)" ::: "memory");
    SCHEDB; BARRIER; SCHEDB;
    const u16* Asc = &As[kt & 1][0];
    const u16* Bsc = &Bs[kt & 1][0];
#pragma unroll
    for (int h = 0; h < 2; h++){
      short8 af[4], bfr[4];
#pragma unroll
      for (int mi = 0; mi < 4; mi++){
        int m = wm * 64 + mi * 16 + l15;
        af[mi] = *(const short8*)(Asc + m * 64 + (((h * 4 + g) ^ (m & 7)) << 3));
      }
#pragma unroll
      for (int ni = 0; ni < 4; ni++){
        int n = wn * 64 + ni * 16 + l15;
        bfr[ni] = *(const short8*)(Bsc + n * 64 + (((h * 4 + g) ^ (n & 7)) << 3));
      }
      __builtin_amdgcn_s_setprio(1);
#pragma unroll
      for (int mi = 0; mi < 4; mi++)
#pragma unroll
        for (int ni = 0; ni < 4; ni++)
          acc[mi][ni] = __builtin_amdgcn_mfma_f32_16x16x32_bf16(af[mi], bfr[ni], acc[mi][ni], 0, 0, 0);
      __builtin_amdgcn_s_setprio(0);
    }
    asm volatile("s_waitcnt lgkmcnt(0)" ::: "memory");
    SCHEDB; BARRIER; SCHEDB;
    if (kt + 2 < KT) STAGE(kt & 1, kt + 2);
  }

#pragma unroll
  for (int mi = 0; mi < 4; mi++){
#pragma unroll
    for (int ni = 0; ni < 4; ni++){
      int col = n0 + wn * 64 + ni * 16 + l15;
#pragma unroll
      for (int r = 0; r < 4; r++){
        int row = m0 + wm * 64 + mi * 16 + g * 4 + r;
        outf[(size_t)row * N + col] = acc[mi][ni][r];
      }
    }
  }
}

// ---------------- flash block-causal attention (R10 schedule, log2 softmax) ----------------
__global__ __launch_bounds__(512, 4) void k_attn(const u16* __restrict__ qkv2,
                                                 const u16* __restrict__ vt2,
                                                 u16* __restrict__ ao){
  __shared__ u16 Ks[2][8192];   // [kv=128][hd=64] per buf, XOR-swizzled chunks (32KB)
  __shared__ u16 Vs[8192];      // [d=64][kv=128], XOR-swizzled chunks (16KB)
  __shared__ u16 Ps[8][1024];   // per-wave P half [16q][64kv], swizzle ^((q&7)<<4) (16KB)

  int bid = blockIdx.x;
  int bh = bid & 31;                          // bid%8 stable -> same-bh on same XCD
  int idx = (bid >> 5) & 7;
  int half = bid >> 8;
  int qb = half ? idx : 15 - idx;
  int b = bh >> 4, h = bh & 15;
  int t = threadIdx.x, wv = t >> 6, lane = t & 63, l15 = lane & 15, g = lane >> 4;

  int qrow = qb * 128 + wv * 16 + l15;
  const u16* qp = qkv2 + (size_t)(b * N_ + qrow) * NQK_ + h * 64 + g * 8;
  short8 qfa = *(const short8*)qp;        // roped + (1/8)*log2e-scaled by gemm1
  short8 qfb = *(const short8*)(qp + 32);

  char* Pw = (char*)&Ps[wv][0];
  const u16* vb_ = vt2 + (size_t)bh * 4096 * 32;   // vt2[bh][nc][d][32]

  auto STAGE_K = [&](int buf, int j) {
#pragma unroll
    for (int i = 0; i < 2; i++){
      int c = (i * 8 + wv) * 64 + lane;
      int kv = c >> 3, pos = c & 7;
      GLL16(qkv2 + (size_t)(b * N_ + j * 128 + kv) * NQK_ + DIM_ + h * 64 + ((pos ^ (kv & 7)) << 3),
            &Ks[buf][(i * 8 + wv) * 512]);
    }
  };
  auto STAGE_V = [&](int j) {
#pragma unroll
    for (int i = 0; i < 2; i++){
      int c = (wv * 2 + i) * 64 + lane;
      int d = c >> 4;
      int lc = (c & 15) ^ (d & 7);
      GLL16(vb_ + ((size_t)((j * 4 + (lc >> 2)) * 64 + d) * 32) + ((lc & 3) << 3),
            &Vs[(wv * 2 + i) * 512]);
    }
  };

  f32x4 oacc[4] = {};
  float m_run = -INFINITY, l_run = 0.0f;

  STAGE_K(0, 0);
  __syncthreads();
  int cur = 0;

  for (int j = 0; j <= qb; j++){
    STAGE_V(j);                                // issues 2 loads (oldest)
    if (j < qb) STAGE_K(cur ^ 1, j + 1);       // issues 2 more (newest)
    const u16* K = &Ks[cur][0];

    f32x4 sv[8];
    __builtin_amdgcn_s_setprio(1);
#pragma unroll
    for (int s = 0; s < 8; s++){
      int kvr = s * 16 + l15;
      short8 kf0 = *(const short8*)(K + kvr * 64 + ((g ^ (kvr & 7)) << 3));
      short8 kf1 = *(const short8*)(K + kvr * 64 + (((4 + g) ^ (kvr & 7)) << 3));
      f32x4 z = {0.f, 0.f, 0.f, 0.f};
      z = __builtin_amdgcn_mfma_f32_16x16x32_bf16(kf0, qfa, z, 0, 0, 0);
      z = __builtin_amdgcn_mfma_f32_16x16x32_bf16(kf1, qfb, z, 0, 0, 0);
      sv[s] = z;
    }
    __builtin_amdgcn_s_setprio(0);

    // online softmax in log2 domain; defer-max THR = 8*log2(e)
    float mt = -INFINITY;
#pragma unroll
    for (int s = 0; s < 8; s++)
#pragma unroll
      for (int r = 0; r < 4; r++) mt = fmaxf(mt, sv[s][r]);
    mt = fmaxf(mt, __shfl_xor(mt, 16, 64));
    mt = fmaxf(mt, __shfl_xor(mt, 32, 64));
    if (!__all(mt <= m_run + 11.5415603f)){
      float m_new = fmaxf(m_run, mt);
      float alpha = exp2f(m_run - m_new);
      float af4[4];
#pragma unroll
      for (int r = 0; r < 4; r++) af4[r] = __shfl(alpha, g * 4 + r, 64);
#pragma unroll
      for (int ni = 0; ni < 4; ni++)
#pragma unroll
        for (int r = 0; r < 4; r++) oacc[ni][r] *= af4[r];
      l_run *= alpha;
      m_run = m_new;
    }
    float psum = 0.0f;
#pragma unroll
    for (int s = 0; s < 8; s++)
#pragma unroll
      for (int r = 0; r < 4; r++){
        float p = exp2f(sv[s][r] - m_run);
        sv[s][r] = p;
        psum += p;
      }
    psum += __shfl_xor(psum, 16, 64);
    psum += __shfl_xor(psum, 32, 64);
    l_run += psum;

    // V(j) landed (own oldest 2 loads); K(j+1) stays in flight through PV
    if (j < qb) asm volatile("s_waitcnt vmcnt(2)" ::: "memory");
    else        asm volatile("s_waitcnt vmcnt(0)" ::: "memory");
    SCHEDB; BARRIER; SCHEDB;

#pragma unroll
    for (int hf = 0; hf < 2; hf++){
#pragma unroll
      for (int s2 = 0; s2 < 4; s2++){
        int s = hf * 4 + s2;
        uint2 pk;
        pk.x = cvtpk(sv[s][0], sv[s][1]);
        pk.y = cvtpk(sv[s][2], sv[s][3]);
        int byte = (l15 * 128 + s2 * 32 + g * 8) ^ ((l15 & 7) << 4);
        *(uint2*)(Pw + byte) = pk;
      }
      __builtin_amdgcn_s_setprio(1);
#pragma unroll
      for (int cc2 = 0; cc2 < 2; cc2++){
        int cc = hf * 2 + cc2;
        int rb = (l15 * 128 + cc2 * 64 + g * 16) ^ ((l15 & 7) << 4);
        short8 pa = *(const short8*)(Pw + rb);
#pragma unroll
        for (int ni = 0; ni < 4; ni++){
          int d = ni * 16 + l15;
          short8 vf = *(const short8*)(Vs + d * 128 + (((cc * 4 + g) ^ (d & 7)) << 3));
          oacc[ni] = __builtin_amdgcn_mfma_f32_16x16x32_bf16(pa, vf, oacc[ni], 0, 0, 0);
        }
      }
      __builtin_amdgcn_s_setprio(0);
    }

    __syncthreads();   // all waves done with Vs / Ks[cur]; K(j+1) drained (flew full tile)
    cur ^= 1;
  }

  float lf[4];
#pragma unroll
  for (int r = 0; r < 4; r++) lf[r] = 1.0f / __shfl(l_run, g * 4 + r, 64);
#pragma unroll
  for (int ni = 0; ni < 4; ni++)
#pragma unroll
    for (int r = 0; r < 4; r++){
      size_t idxo = (size_t)(b * N_ + qb * 128 + wv * 16 + g * 4 + r) * DIM_ + h * 64 + ni * 16 + l15;
      ao[idxo] = f2bf(oacc[ni][r] * lf[r]);
    }
}

// ---------------- launch ----------------
extern "C" void kernel_launch(void* const* d_in, const int* in_sizes, int n_in,
                              void* d_out, int out_size, void* d_ws, size_t ws_size,
                              hipStream_t stream){
  const float* x      = (const float*)d_in[0];
  const float* norm_w = (const float*)d_in[1];
  const float* w_qkv  = (const float*)d_in[2];
  const float* w_out  = (const float*)d_in[3];
  float* out0 = (float*)d_out;                      // [B,N,DIM] fp32
  float* out1 = out0 + (size_t)NR_ * DIM_;          // orig_v [B,H,N,DH] fp32

  char* ws = (char*)d_ws;
  u16* xn    = (u16*)(ws + 0);           // 8 MB (reused as attn-out after GEMM1)
  u16* wqkvT = (u16*)(ws + 8388608);     // 6 MB
  u16* woutT = (u16*)(ws + 14680064);    // 2 MB
  u16* qkv2  = (u16*)(ws + 16777216);    // 16 MB  [row][2048] roped q|k bf16
  u16* vt2   = (u16*)(ws + 33554432);    // 8 MB   [bh][64][64][32] bf16
  float2* cs = (float2*)(ws + 41943040); // 0.5 MB
  u16* ao    = xn;                       // alias: xn dead after GEMM1

  k_rmsnorm<<<NR_, 256, 0, stream>>>(x, norm_w, xn);
  k_tcast<<<dim3(NQKV_ / 64, DIM_ / 64), 256, 0, stream>>>(w_qkv, wqkvT, DIM_, NQKV_);
  k_tcast<<<dim3(DIM_ / 64, DIM_ / 64), 256, 0, stream>>>(w_out, woutT, DIM_, DIM_);
  k_cs<<<(N_ * 32) / 256, 256, 0, stream>>>(cs);
  k_gemm1<<<256, 512, 0, stream>>>(xn, wqkvT, qkv2, out1, vt2, cs);
  k_attn<<<512, 512, 0, stream>>>(qkv2, vt2, ao);
  k_gemm2<<<256, 256, 0, stream>>>(ao, woutT, out0);
}

// Round 15
// 126.496 us; speedup vs baseline: 1.0691x; 1.0691x over previous
//
#include <hip/hip_runtime.h>
#include <stdint.h>

#define B_    2
#define N_    2048
#define DIM_  1024
#define H_    16
#define DH_   64
#define NR_   4096     // B*N rows
#define NQKV_ 3072
#define NQK_  2048     // q,k columns kept in qkv2

typedef unsigned short u16;
typedef __attribute__((ext_vector_type(8))) short short8;
typedef __attribute__((ext_vector_type(4))) float f32x4;

static __device__ __forceinline__ u16 f2bf(float f){
  union { float f; uint32_t u; } x; x.f = f;
  return (u16)((x.u + 0x7fffu + ((x.u >> 16) & 1u)) >> 16);
}
static __device__ __forceinline__ float bf2f(uint32_t b){
  union { uint32_t u; float f; } x; x.u = b << 16;
  return x.f;
}
// hardware packed f32->bf16 (RNE): D = {lo: bf16(a), hi: bf16(b)}
static __device__ __forceinline__ uint32_t cvtpk(float a, float b){
  uint32_t r;
  asm("v_cvt_pk_bf16_f32 %0, %1, %2" : "=v"(r) : "v"(a), "v"(b));
  return r;
}

// global -> LDS direct copy, 16B per lane; LDS dest is wave-uniform base + lane*16
#define GLL16(gp, lp) __builtin_amdgcn_global_load_lds( \
    (const __attribute__((address_space(1))) void*)(gp), \
    (__attribute__((address_space(3))) void*)(lp), 16, 0, 0)

#define SCHEDB __builtin_amdgcn_sched_barrier(0)
#define BARRIER __builtin_amdgcn_s_barrier()

// ---------------- RMSNorm + cast to bf16 ----------------
__global__ __launch_bounds__(256) void k_rmsnorm(const float* __restrict__ x,
                                                 const float* __restrict__ w,
                                                 u16* __restrict__ xn){
  int row = blockIdx.x;
  int t = threadIdx.x;
  float4 v = ((const float4*)(x + (size_t)row * DIM_))[t];
  float ss = v.x*v.x + v.y*v.y + v.z*v.z + v.w*v.w;
#pragma unroll
  for (int m = 1; m < 64; m <<= 1) ss += __shfl_xor(ss, m, 64);
  __shared__ float red[4];
  if ((t & 63) == 0) red[t >> 6] = ss;
  __syncthreads();
  float tot = red[0] + red[1] + red[2] + red[3];
  float r = rsqrtf(tot * (1.0f / DIM_) + 1.1920929e-07f);
  float4 wv = ((const float4*)w)[t];
  union { u16 u[4]; uint2 v2; } o;
  o.u[0] = f2bf(v.x * r * wv.x);
  o.u[1] = f2bf(v.y * r * wv.y);
  o.u[2] = f2bf(v.z * r * wv.z);
  o.u[3] = f2bf(v.w * r * wv.w);
  ((uint2*)(xn + (size_t)row * DIM_))[t] = o.v2;
}

// ---------------- fp32 [R][C] -> bf16 [C][R] transpose-cast ----------------
__global__ __launch_bounds__(256) void k_tcast(const float* __restrict__ src,
                                               u16* __restrict__ dst, int R, int C){
  __shared__ float ls[64][65];
  int c0 = blockIdx.x * 64, r0 = blockIdx.y * 64;
  int t = threadIdx.x;
  int rr = t >> 2, q = t & 3;
  const float* s = src + (size_t)(r0 + rr) * C + c0 + q * 16;
#pragma unroll
  for (int j = 0; j < 4; j++){
    float4 v = ((const float4*)s)[j];
    ls[rr][q*16 + j*4 + 0] = v.x;
    ls[rr][q*16 + j*4 + 1] = v.y;
    ls[rr][q*16 + j*4 + 2] = v.z;
    ls[rr][q*16 + j*4 + 3] = v.w;
  }
  __syncthreads();
  int cc = t >> 2;
  union { u16 u[16]; uint4 v4[2]; } o;
#pragma unroll
  for (int i = 0; i < 16; i++) o.u[i] = f2bf(ls[q*16 + i][cc]);
  u16* d = dst + (size_t)(c0 + cc) * R + r0 + q * 16;
  ((uint4*)d)[0] = o.v4[0];
  ((uint4*)d)[1] = o.v4[1];
}

// ---------------- cos/sin table [N][32] ----------------
__global__ void k_cs(float2* __restrict__ cs){
  int tid = blockIdx.x * blockDim.x + threadIdx.x;
  if (tid >= N_ * 32) return;
  int n = tid >> 5, i = tid & 31;
  float inv = powf(10000.0f, -(float)(2 * i) * (1.0f / 64.0f));
  float a = (float)n * inv;
  cs[tid] = make_float2(cosf(a), sinf(a));
}

// ---------------- GEMM1: 128x192 tile, BK=64, counted-vmcnt, grid 512 (R13) ----------------
// C[4096,3072] = xn @ wqkvT^T. Epilogue: cols<2048 -> fused interleaved RoPE
// (q scaled by 0.125*log2e -> log2-domain scores) -> bf16 qkv2;
// cols>=2048 -> fp32 orig_v + bf16 vT2 tiled.
__global__ __launch_bounds__(256, 2) void k_gemm1(const u16* __restrict__ A,
                                                  const u16* __restrict__ Bt,
                                                  u16* __restrict__ outb,
                                                  float* __restrict__ outf,
                                                  u16* __restrict__ vt2,
                                                  const float2* __restrict__ cs){
  __shared__ u16 As[2][8192];    // [128 m][64 k] per buf, chunk-XOR swizzle (32KB)
  __shared__ u16 Bs[2][12288];   // [192 n][64 k] per buf (48KB)
  const int K = 1024, KT = 16;

  int xcd = blockIdx.x & 7, c = blockIdx.x >> 3;       // c in 0..63
  int m0 = ((xcd >> 1) * 8 + (c >> 3)) << 7;           // m-panel 0..31 (128 rows)
  int n0 = ((xcd & 1) * 8 + (c & 7)) * 192;            // n-panel 0..15 (192 cols)

  int t = threadIdx.x, wv = t >> 6, lane = t & 63, l15 = lane & 15, g = lane >> 4;
  int wm = wv >> 1, wn = wv & 1;

  auto STAGE = [&](int buf, int kt){
    int k0 = kt << 6;
#pragma unroll
    for (int i = 0; i < 4; i++){           // A: 128 rows x 64 k = 16KB
      int cc = (i * 4 + wv) * 64 + lane;
      int m = cc >> 3, pos = cc & 7;
      GLL16(A + (size_t)(m0 + m) * K + k0 + ((pos ^ (m & 7)) << 3), &As[buf][(i * 4 + wv) * 512]);
    }
#pragma unroll
    for (int i = 0; i < 6; i++){           // B: 192 rows x 64 k = 24KB
      int cc = (i * 4 + wv) * 64 + lane;
      int n = cc >> 3, pos = cc & 7;
      GLL16(Bt + (size_t)(n0 + n) * K + k0 + ((pos ^ (n & 7)) << 3), &Bs[buf][(i * 4 + wv) * 512]);
    }
  };

  f32x4 acc[4][6] = {};
  STAGE(0, 0);
  STAGE(1, 1);

  for (int kt = 0; kt < KT; kt++){
    if (kt < KT - 1) asm volatile("s_waitcnt vmcnt(10)" ::: "memory");
    else             asm volatile("s_waitcnt vmcnt(0)" ::: "memory");
    SCHEDB; BARRIER; SCHEDB;
    const u16* Asc = &As[kt & 1][0];
    const u16* Bsc = &Bs[kt & 1][0];
#pragma unroll
    for (int h = 0; h < 2; h++){
      short8 af[4], bfr[6];
#pragma unroll
      for (int mi = 0; mi < 4; mi++){
        int m = wm * 64 + mi * 16 + l15;
        af[mi] = *(const short8*)(Asc + m * 64 + (((h * 4 + g) ^ (m & 7)) << 3));
      }
#pragma unroll
      for (int ni = 0; ni < 6; ni++){
        int n = wn * 96 + ni * 16 + l15;
        bfr[ni] = *(const short8*)(Bsc + n * 64 + (((h * 4 + g) ^ (n & 7)) << 3));
      }
      __builtin_amdgcn_s_setprio(1);
#pragma unroll
      for (int mi = 0; mi < 4; mi++)
#pragma unroll
        for (int ni = 0; ni < 6; ni++)
          acc[mi][ni] = __builtin_amdgcn_mfma_f32_16x16x32_bf16(af[mi], bfr[ni], acc[mi][ni], 0, 0, 0);
      __builtin_amdgcn_s_setprio(0);
    }
    asm volatile("s_waitcnt lgkmcnt(0)" ::: "memory");
    SCHEDB; BARRIER; SCHEDB;
    if (kt + 2 < KT) STAGE(kt & 1, kt + 2);
  }

#pragma unroll
  for (int mi = 0; mi < 4; mi++){
#pragma unroll
    for (int ni = 0; ni < 6; ni++){
      int col = n0 + wn * 96 + ni * 16 + l15;
#pragma unroll
      for (int r = 0; r < 4; r++){
        int row = m0 + wm * 64 + mi * 16 + g * 4 + r;
        float val = acc[mi][ni][r];
        if (col < NQK_){
          // fused interleaved RoPE: partner element lives in adjacent lane
          int n = row & (N_ - 1);
          int dpair = (col & 63) >> 1;
          float2 cv = cs[(size_t)n * 32 + dpair];
          float partner = __shfl_xor(val, 1, 64);
          float y = (l15 & 1) ? (val * cv.x + partner * cv.y)
                              : (val * cv.x - partner * cv.y);
          if (col < DIM_) y *= 0.18033688f;   // (1/8)*log2(e): log2-domain scores
          outb[(size_t)row * NQK_ + col] = f2bf(y);
        } else {
          int hh = (col - 2 * DIM_) >> 6, d = col & 63;
          int b = row >> 11, n = row & (N_ - 1);
          outf[((size_t)((b * H_ + hh) * N_ + n) << 6) + d] = val;
          // vT2 tiled: [bh][n>>5][d][n&31]
          vt2[((size_t)((b * H_ + hh) * 64 + (n >> 5)) * 64 + d) * 32 + (n & 31)] = f2bf(val);
        }
      }
    }
  }
}

// ---------------- GEMM2: 128x128 tile, BK=128, counted-vmcnt, grid 256 ----------------
// out0[4096,1024] fp32 = ao @ woutT^T. Grid 256 = 1 block/CU (grid-limited), so
// 128KB LDS is free; BK=128 halves barrier/wait events (64 MFMA per barrier pair)
// and doubles the flight window for the prefetched tile (vmcnt(16)).
// Row = 16 chunks of 16B; swizzle chunk ^= (row&15) (involution both sides).
__global__ __launch_bounds__(256) void k_gemm2(const u16* __restrict__ A,
                                               const u16* __restrict__ Bt,
                                               float* __restrict__ outf){
  __shared__ u16 As[2][16384];   // [128 m][128 k] per buf (32KB each)
  __shared__ u16 Bs[2][16384];   // [128 n][128 k] per buf (32KB each)
  const int K = 1024, KT = 8, N = 1024;

  int xcd = blockIdx.x & 7, c = blockIdx.x >> 3;       // c in 0..31
  int m0 = (xcd * 4 + (c >> 3)) << 7;
  int n0 = (c & 7) << 7;

  int t = threadIdx.x, wv = t >> 6, lane = t & 63, l15 = lane & 15, g = lane >> 4;
  int wm = wv >> 1, wn = wv & 1;

  // stage one 128x128 bf16 tile (32KB): 8 gload_lds per wave per matrix.
  auto STAGE = [&](int buf, int kt){
    int k0 = kt << 7;
#pragma unroll
    for (int i = 0; i < 8; i++){
      int s = (i * 4 + wv) * 64 + lane;        // slot 0..2047
      int m = s >> 4;                          // row
      int lc = (s & 15) ^ (m & 15);            // logical chunk
      GLL16(A + (size_t)(m0 + m) * K + k0 + (lc << 3), &As[buf][(i * 4 + wv) * 512]);
    }
#pragma unroll
    for (int i = 0; i < 8; i++){
      int s = (i * 4 + wv) * 64 + lane;
      int n = s >> 4;
      int lc = (s & 15) ^ (n & 15);
      GLL16(Bt + (size_t)(n0 + n) * K + k0 + (lc << 3), &Bs[buf][(i * 4 + wv) * 512]);
    }
  };

  f32x4 acc[4][4] = {};
  STAGE(0, 0);
  STAGE(1, 1);

  for (int kt = 0; kt < KT; kt++){
    if (kt < KT - 1) asm volatile("s_waitcnt vmcnt(16)" ::: "memory");
    else             asm volatile("s_waitcnt vmcnt(0)" ::: "memory");
    SCHEDB; BARRIER; SCHEDB;
    const u16* Asc = &As[kt & 1][0];
    const u16* Bsc = &Bs[kt & 1][0];
#pragma unroll
    for (int h = 0; h < 4; h++){               // 4 k-steps of 32
      short8 af[4], bfr[4];
#pragma unroll
      for (int mi = 0; mi < 4; mi++){
        int m = wm * 64 + mi * 16 + l15;
        af[mi] = *(const short8*)(Asc + m * 128 + (((h * 4 + g) ^ (m & 15)) << 3));
      }
#pragma unroll
      for (int ni = 0; ni < 4; ni++){
        int n = wn * 64 + ni * 16 + l15;
        bfr[ni] = *(const short8*)(Bsc + n * 128 + (((h * 4 + g) ^ (n & 15)) << 3));
      }
      __builtin_amdgcn_s_setprio(1);
#pragma unroll
      for (int mi = 0; mi < 4; mi++)
#pragma unroll
        for (int ni = 0; ni < 4; ni++)
          acc[mi][ni] = __builtin_amdgcn_mfma_f32_16x16x32_bf16(af[mi], bfr[ni], acc[mi][ni], 0, 0, 0);
      __builtin_amdgcn_s_setprio(0);
    }
    asm volatile("s_waitcnt lgkmcnt(0)" ::: "memory");
    SCHEDB; BARRIER; SCHEDB;
    if (kt + 2 < KT) STAGE(kt & 1, kt + 2);
  }

#pragma unroll
  for (int mi = 0; mi < 4; mi++){
#pragma unroll
    for (int ni = 0; ni < 4; ni++){
      int col = n0 + wn * 64 + ni * 16 + l15;
#pragma unroll
      for (int r = 0; r < 4; r++){
        int row = m0 + wm * 64 + mi * 16 + g * 4 + r;
        outf[(size_t)row * N + col] = acc[mi][ni][r];
      }
    }
  }
}

// ---------------- flash block-causal attention (R10 schedule, log2 softmax) ----------------
__global__ __launch_bounds__(512, 4) void k_attn(const u16* __restrict__ qkv2,
                                                 const u16* __restrict__ vt2,
                                                 u16* __restrict__ ao){
  __shared__ u16 Ks[2][8192];   // [kv=128][hd=64] per buf, XOR-swizzled chunks (32KB)
  __shared__ u16 Vs[8192];      // [d=64][kv=128], XOR-swizzled chunks (16KB)
  __shared__ u16 Ps[8][1024];   // per-wave P half [16q][64kv], swizzle ^((q&7)<<4) (16KB)

  int bid = blockIdx.x;
  int bh = bid & 31;                          // bid%8 stable -> same-bh on same XCD
  int idx = (bid >> 5) & 7;
  int half = bid >> 8;
  int qb = half ? idx : 15 - idx;
  int b = bh >> 4, h = bh & 15;
  int t = threadIdx.x, wv = t >> 6, lane = t & 63, l15 = lane & 15, g = lane >> 4;

  int qrow = qb * 128 + wv * 16 + l15;
  const u16* qp = qkv2 + (size_t)(b * N_ + qrow) * NQK_ + h * 64 + g * 8;
  short8 qfa = *(const short8*)qp;        // roped + (1/8)*log2e-scaled by gemm1
  short8 qfb = *(const short8*)(qp + 32);

  char* Pw = (char*)&Ps[wv][0];
  const u16* vb_ = vt2 + (size_t)bh * 4096 * 32;   // vt2[bh][nc][d][32]

  auto STAGE_K = [&](int buf, int j) {
#pragma unroll
    for (int i = 0; i < 2; i++){
      int c = (i * 8 + wv) * 64 + lane;
      int kv = c >> 3, pos = c & 7;
      GLL16(qkv2 + (size_t)(b * N_ + j * 128 + kv) * NQK_ + DIM_ + h * 64 + ((pos ^ (kv & 7)) << 3),
            &Ks[buf][(i * 8 + wv) * 512]);
    }
  };
  auto STAGE_V = [&](int j) {
#pragma unroll
    for (int i = 0; i < 2; i++){
      int c = (wv * 2 + i) * 64 + lane;
      int d = c >> 4;
      int lc = (c & 15) ^ (d & 7);
      GLL16(vb_ + ((size_t)((j * 4 + (lc >> 2)) * 64 + d) * 32) + ((lc & 3) << 3),
            &Vs[(wv * 2 + i) * 512]);
    }
  };

  f32x4 oacc[4] = {};
  float m_run = -INFINITY, l_run = 0.0f;

  STAGE_K(0, 0);
  __syncthreads();
  int cur = 0;

  for (int j = 0; j <= qb; j++){
    STAGE_V(j);                                // issues 2 loads (oldest)
    if (j < qb) STAGE_K(cur ^ 1, j + 1);       // issues 2 more (newest)
    const u16* K = &Ks[cur][0];

    f32x4 sv[8];
    __builtin_amdgcn_s_setprio(1);
#pragma unroll
    for (int s = 0; s < 8; s++){
      int kvr = s * 16 + l15;
      short8 kf0 = *(const short8*)(K + kvr * 64 + ((g ^ (kvr & 7)) << 3));
      short8 kf1 = *(const short8*)(K + kvr * 64 + (((4 + g) ^ (kvr & 7)) << 3));
      f32x4 z = {0.f, 0.f, 0.f, 0.f};
      z = __builtin_amdgcn_mfma_f32_16x16x32_bf16(kf0, qfa, z, 0, 0, 0);
      z = __builtin_amdgcn_mfma_f32_16x16x32_bf16(kf1, qfb, z, 0, 0, 0);
      sv[s] = z;
    }
    __builtin_amdgcn_s_setprio(0);

    // online softmax in log2 domain; defer-max THR = 8*log2(e)
    float mt = -INFINITY;
#pragma unroll
    for (int s = 0; s < 8; s++)
#pragma unroll
      for (int r = 0; r < 4; r++) mt = fmaxf(mt, sv[s][r]);
    mt = fmaxf(mt, __shfl_xor(mt, 16, 64));
    mt = fmaxf(mt, __shfl_xor(mt, 32, 64));
    if (!__all(mt <= m_run + 11.5415603f)){
      float m_new = fmaxf(m_run, mt);
      float alpha = exp2f(m_run - m_new);
      float af4[4];
#pragma unroll
      for (int r = 0; r < 4; r++) af4[r] = __shfl(alpha, g * 4 + r, 64);
#pragma unroll
      for (int ni = 0; ni < 4; ni++)
#pragma unroll
        for (int r = 0; r < 4; r++) oacc[ni][r] *= af4[r];
      l_run *= alpha;
      m_run = m_new;
    }
    float psum = 0.0f;
#pragma unroll
    for (int s = 0; s < 8; s++)
#pragma unroll
      for (int r = 0; r < 4; r++){
        float p = exp2f(sv[s][r] - m_run);
        sv[s][r] = p;
        psum += p;
      }
    psum += __shfl_xor(psum, 16, 64);
    psum += __shfl_xor(psum, 32, 64);
    l_run += psum;

    // V(j) landed (own oldest 2 loads); K(j+1) stays in flight through PV
    if (j < qb) asm volatile("s_waitcnt vmcnt(2)" ::: "memory");
    else        asm volatile("s_waitcnt vmcnt(0)" ::: "memory");
    SCHEDB; BARRIER; SCHEDB;

#pragma unroll
    for (int hf = 0; hf < 2; hf++){
#pragma unroll
      for (int s2 = 0; s2 < 4; s2++){
        int s = hf * 4 + s2;
        uint2 pk;
        pk.x = cvtpk(sv[s][0], sv[s][1]);
        pk.y = cvtpk(sv[s][2], sv[s][3]);
        int byte = (l15 * 128 + s2 * 32 + g * 8) ^ ((l15 & 7) << 4);
        *(uint2*)(Pw + byte) = pk;
      }
      __builtin_amdgcn_s_setprio(1);
#pragma unroll
      for (int cc2 = 0; cc2 < 2; cc2++){
        int cc = hf * 2 + cc2;
        int rb = (l15 * 128 + cc2 * 64 + g * 16) ^ ((l15 & 7) << 4);
        short8 pa = *(const short8*)(Pw + rb);
#pragma unroll
        for (int ni = 0; ni < 4; ni++){
          int d = ni * 16 + l15;
          short8 vf = *(const short8*)(Vs + d * 128 + (((cc * 4 + g) ^ (d & 7)) << 3));
          oacc[ni] = __builtin_amdgcn_mfma_f32_16x16x32_bf16(pa, vf, oacc[ni], 0, 0, 0);
        }
      }
      __builtin_amdgcn_s_setprio(0);
    }

    __syncthreads();   // all waves done with Vs / Ks[cur]; K(j+1) drained (flew full tile)
    cur ^= 1;
  }

  float lf[4];
#pragma unroll
  for (int r = 0; r < 4; r++) lf[r] = 1.0f / __shfl(l_run, g * 4 + r, 64);
#pragma unroll
  for (int ni = 0; ni < 4; ni++)
#pragma unroll
    for (int r = 0; r < 4; r++){
      size_t idxo = (size_t)(b * N_ + qb * 128 + wv * 16 + g * 4 + r) * DIM_ + h * 64 + ni * 16 + l15;
      ao[idxo] = f2bf(oacc[ni][r] * lf[r]);
    }
}

// ---------------- launch ----------------
extern "C" void kernel_launch(void* const* d_in, const int* in_sizes, int n_in,
                              void* d_out, int out_size, void* d_ws, size_t ws_size,
                              hipStream_t stream){
  const float* x      = (const float*)d_in[0];
  const float* norm_w = (const float*)d_in[1];
  const float* w_qkv  = (const float*)d_in[2];
  const float* w_out  = (const float*)d_in[3];
  float* out0 = (float*)d_out;                      // [B,N,DIM] fp32
  float* out1 = out0 + (size_t)NR_ * DIM_;          // orig_v [B,H,N,DH] fp32

  char* ws = (char*)d_ws;
  u16* xn    = (u16*)(ws + 0);           // 8 MB (reused as attn-out after GEMM1)
  u16* wqkvT = (u16*)(ws + 8388608);     // 6 MB
  u16* woutT = (u16*)(ws + 14680064);    // 2 MB
  u16* qkv2  = (u16*)(ws + 16777216);    // 16 MB  [row][2048] roped q|k bf16
  u16* vt2   = (u16*)(ws + 33554432);    // 8 MB   [bh][64][64][32] bf16
  float2* cs = (float2*)(ws + 41943040); // 0.5 MB
  u16* ao    = xn;                       // alias: xn dead after GEMM1

  k_rmsnorm<<<NR_, 256, 0, stream>>>(x, norm_w, xn);
  k_tcast<<<dim3(NQKV_ / 64, DIM_ / 64), 256, 0, stream>>>(w_qkv, wqkvT, DIM_, NQKV_);
  k_tcast<<<dim3(DIM_ / 64, DIM_ / 64), 256, 0, stream>>>(w_out, woutT, DIM_, DIM_);
  k_cs<<<(N_ * 32) / 256, 256, 0, stream>>>(cs);
  k_gemm1<<<512, 256, 0, stream>>>(xn, wqkvT, qkv2, out1, vt2, cs);
  k_attn<<<512, 512, 0, stream>>>(qkv2, vt2, ao);
  k_gemm2<<<256, 256, 0, stream>>>(ao, woutT, out0);
}

// Round 16
// 122.925 us; speedup vs baseline: 1.1001x; 1.0291x over previous
//
#include <hip/hip_runtime.h>
#include <stdint.h>

#define B_    2
#define N_    2048
#define DIM_  1024
#define H_    16
#define DH_   64
#define NR_   4096     // B*N rows
#define NQKV_ 3072
#define NQK_  2048     // q,k columns kept in qkv2

typedef unsigned short u16;
typedef __attribute__((ext_vector_type(8))) short short8;
typedef __attribute__((ext_vector_type(4))) float f32x4;

static __device__ __forceinline__ u16 f2bf(float f){
  union { float f; uint32_t u; } x; x.f = f;
  return (u16)((x.u + 0x7fffu + ((x.u >> 16) & 1u)) >> 16);
}
static __device__ __forceinline__ float bf2f(uint32_t b){
  union { uint32_t u; float f; } x; x.u = b << 16;
  return x.f;
}
// hardware packed f32->bf16 (RNE): D = {lo: bf16(a), hi: bf16(b)}
static __device__ __forceinline__ uint32_t cvtpk(float a, float b){
  uint32_t r;
  asm("v_cvt_pk_bf16_f32 %0, %1, %2" : "=v"(r) : "v"(a), "v"(b));
  return r;
}

// global -> LDS direct copy, 16B per lane; LDS dest is wave-uniform base + lane*16
#define GLL16(gp, lp) __builtin_amdgcn_global_load_lds( \
    (const __attribute__((address_space(1))) void*)(gp), \
    (__attribute__((address_space(3))) void*)(lp), 16, 0, 0)

#define SCHEDB __builtin_amdgcn_sched_barrier(0)
#define BARRIER __builtin_amdgcn_s_barrier()

// ---------------- RMSNorm + cast to bf16 ----------------
__global__ __launch_bounds__(256) void k_rmsnorm(const float* __restrict__ x,
                                                 const float* __restrict__ w,
                                                 u16* __restrict__ xn){
  int row = blockIdx.x;
  int t = threadIdx.x;
  float4 v = ((const float4*)(x + (size_t)row * DIM_))[t];
  float ss = v.x*v.x + v.y*v.y + v.z*v.z + v.w*v.w;
#pragma unroll
  for (int m = 1; m < 64; m <<= 1) ss += __shfl_xor(ss, m, 64);
  __shared__ float red[4];
  if ((t & 63) == 0) red[t >> 6] = ss;
  __syncthreads();
  float tot = red[0] + red[1] + red[2] + red[3];
  float r = rsqrtf(tot * (1.0f / DIM_) + 1.1920929e-07f);
  float4 wv = ((const float4*)w)[t];
  union { u16 u[4]; uint2 v2; } o;
  o.u[0] = f2bf(v.x * r * wv.x);
  o.u[1] = f2bf(v.y * r * wv.y);
  o.u[2] = f2bf(v.z * r * wv.z);
  o.u[3] = f2bf(v.w * r * wv.w);
  ((uint2*)(xn + (size_t)row * DIM_))[t] = o.v2;
}

// ---------------- fused prep: both weight transposes + cos/sin table ----------------
static __device__ __forceinline__ void tcast_body(const float* __restrict__ src,
                                                  u16* __restrict__ dst,
                                                  int R, int C, int c0, int r0, int t){
  __shared__ float ls[64][65];
  int rr = t >> 2, q = t & 3;
  const float* s = src + (size_t)(r0 + rr) * C + c0 + q * 16;
#pragma unroll
  for (int j = 0; j < 4; j++){
    float4 v = ((const float4*)s)[j];
    ls[rr][q*16 + j*4 + 0] = v.x;
    ls[rr][q*16 + j*4 + 1] = v.y;
    ls[rr][q*16 + j*4 + 2] = v.z;
    ls[rr][q*16 + j*4 + 3] = v.w;
  }
  __syncthreads();
  int cc = t >> 2;
  union { u16 u[16]; uint4 v4[2]; } o;
#pragma unroll
  for (int i = 0; i < 16; i++) o.u[i] = f2bf(ls[q*16 + i][cc]);
  u16* d = dst + (size_t)(c0 + cc) * R + r0 + q * 16;
  ((uint4*)d)[0] = o.v4[0];
  ((uint4*)d)[1] = o.v4[1];
}

__global__ __launch_bounds__(256) void k_prep(const float* __restrict__ w_qkv,
                                              const float* __restrict__ w_out,
                                              u16* __restrict__ wqkvT,
                                              u16* __restrict__ woutT,
                                              float2* __restrict__ cs){
  int bid = blockIdx.x;
  int t = threadIdx.x;
  if (bid < 768){
    // w_qkv [1024][3072] -> wqkvT [3072][1024]
    int cb = bid % 48, rb = bid / 48;
    tcast_body(w_qkv, wqkvT, DIM_, NQKV_, cb * 64, rb * 64, t);
  } else if (bid < 1024){
    // w_out [1024][1024] -> woutT [1024][1024]
    int idx = bid - 768;
    int cb = idx & 15, rb = idx >> 4;
    tcast_body(w_out, woutT, DIM_, DIM_, cb * 64, rb * 64, t);
  } else {
    int tid = (bid - 1024) * 256 + t;          // 65536 = N_*32
    int n = tid >> 5, i = tid & 31;
    float inv = powf(10000.0f, -(float)(2 * i) * (1.0f / 64.0f));
    float a = (float)n * inv;
    cs[tid] = make_float2(cosf(a), sinf(a));
  }
}

// ---------------- GEMM1: 128x192 tile, BK=64, counted-vmcnt, grid 512 (R13) ----------------
// C[4096,3072] = xn @ wqkvT^T. Epilogue: cols<2048 -> fused interleaved RoPE
// (q scaled by 0.125*log2e -> log2-domain scores) -> bf16 qkv2;
// cols>=2048 -> fp32 orig_v + bf16 vT2 tiled.
__global__ __launch_bounds__(256, 2) void k_gemm1(const u16* __restrict__ A,
                                                  const u16* __restrict__ Bt,
                                                  u16* __restrict__ outb,
                                                  float* __restrict__ outf,
                                                  u16* __restrict__ vt2,
                                                  const float2* __restrict__ cs){
  __shared__ u16 As[2][8192];    // [128 m][64 k] per buf, chunk-XOR swizzle (32KB)
  __shared__ u16 Bs[2][12288];   // [192 n][64 k] per buf (48KB)
  const int K = 1024, KT = 16;

  int xcd = blockIdx.x & 7, c = blockIdx.x >> 3;       // c in 0..63
  int m0 = ((xcd >> 1) * 8 + (c >> 3)) << 7;           // m-panel 0..31 (128 rows)
  int n0 = ((xcd & 1) * 8 + (c & 7)) * 192;            // n-panel 0..15 (192 cols)

  int t = threadIdx.x, wv = t >> 6, lane = t & 63, l15 = lane & 15, g = lane >> 4;
  int wm = wv >> 1, wn = wv & 1;

  auto STAGE = [&](int buf, int kt){
    int k0 = kt << 6;
#pragma unroll
    for (int i = 0; i < 4; i++){           // A: 128 rows x 64 k = 16KB
      int cc = (i * 4 + wv) * 64 + lane;
      int m = cc >> 3, pos = cc & 7;
      GLL16(A + (size_t)(m0 + m) * K + k0 + ((pos ^ (m & 7)) << 3), &As[buf][(i * 4 + wv) * 512]);
    }
#pragma unroll
    for (int i = 0; i < 6; i++){           // B: 192 rows x 64 k = 24KB
      int cc = (i * 4 + wv) * 64 + lane;
      int n = cc >> 3, pos = cc & 7;
      GLL16(Bt + (size_t)(n0 + n) * K + k0 + ((pos ^ (n & 7)) << 3), &Bs[buf][(i * 4 + wv) * 512]);
    }
  };

  f32x4 acc[4][6] = {};
  STAGE(0, 0);
  STAGE(1, 1);

  for (int kt = 0; kt < KT; kt++){
    if (kt < KT - 1) asm volatile("s_waitcnt vmcnt(10)" ::: "memory");
    else             asm volatile("s_waitcnt vmcnt(0)" ::: "memory");
    SCHEDB; BARRIER; SCHEDB;
    const u16* Asc = &As[kt & 1][0];
    const u16* Bsc = &Bs[kt & 1][0];
#pragma unroll
    for (int h = 0; h < 2; h++){
      short8 af[4], bfr[6];
#pragma unroll
      for (int mi = 0; mi < 4; mi++){
        int m = wm * 64 + mi * 16 + l15;
        af[mi] = *(const short8*)(Asc + m * 64 + (((h * 4 + g) ^ (m & 7)) << 3));
      }
#pragma unroll
      for (int ni = 0; ni < 6; ni++){
        int n = wn * 96 + ni * 16 + l15;
        bfr[ni] = *(const short8*)(Bsc + n * 64 + (((h * 4 + g) ^ (n & 7)) << 3));
      }
      __builtin_amdgcn_s_setprio(1);
#pragma unroll
      for (int mi = 0; mi < 4; mi++)
#pragma unroll
        for (int ni = 0; ni < 6; ni++)
          acc[mi][ni] = __builtin_amdgcn_mfma_f32_16x16x32_bf16(af[mi], bfr[ni], acc[mi][ni], 0, 0, 0);
      __builtin_amdgcn_s_setprio(0);
    }
    asm volatile("s_waitcnt lgkmcnt(0)" ::: "memory");
    SCHEDB; BARRIER; SCHEDB;
    if (kt + 2 < KT) STAGE(kt & 1, kt + 2);
  }

#pragma unroll
  for (int mi = 0; mi < 4; mi++){
#pragma unroll
    for (int ni = 0; ni < 6; ni++){
      int col = n0 + wn * 96 + ni * 16 + l15;
#pragma unroll
      for (int r = 0; r < 4; r++){
        int row = m0 + wm * 64 + mi * 16 + g * 4 + r;
        float val = acc[mi][ni][r];
        if (col < NQK_){
          // fused interleaved RoPE: partner element lives in adjacent lane
          int n = row & (N_ - 1);
          int dpair = (col & 63) >> 1;
          float2 cv = cs[(size_t)n * 32 + dpair];
          float partner = __shfl_xor(val, 1, 64);
          float y = (l15 & 1) ? (val * cv.x + partner * cv.y)
                              : (val * cv.x - partner * cv.y);
          if (col < DIM_) y *= 0.18033688f;   // (1/8)*log2(e): log2-domain scores
          outb[(size_t)row * NQK_ + col] = f2bf(y);
        } else {
          int hh = (col - 2 * DIM_) >> 6, d = col & 63;
          int b = row >> 11, n = row & (N_ - 1);
          outf[((size_t)((b * H_ + hh) * N_ + n) << 6) + d] = val;
          // vT2 tiled: [bh][n>>5][d][n&31]
          vt2[((size_t)((b * H_ + hh) * 64 + (n >> 5)) * 64 + d) * 32 + (n & 31)] = f2bf(val);
        }
      }
    }
  }
}

// ---------------- GEMM2: 128x128 tile, BK=128, counted-vmcnt, grid 256 ----------------
__global__ __launch_bounds__(256) void k_gemm2(const u16* __restrict__ A,
                                               const u16* __restrict__ Bt,
                                               float* __restrict__ outf){
  __shared__ u16 As[2][16384];   // [128 m][128 k] per buf (32KB each)
  __shared__ u16 Bs[2][16384];   // [128 n][128 k] per buf (32KB each)
  const int K = 1024, KT = 8, N = 1024;

  int xcd = blockIdx.x & 7, c = blockIdx.x >> 3;       // c in 0..31
  int m0 = (xcd * 4 + (c >> 3)) << 7;
  int n0 = (c & 7) << 7;

  int t = threadIdx.x, wv = t >> 6, lane = t & 63, l15 = lane & 15, g = lane >> 4;
  int wm = wv >> 1, wn = wv & 1;

  auto STAGE = [&](int buf, int kt){
    int k0 = kt << 7;
#pragma unroll
    for (int i = 0; i < 8; i++){
      int s = (i * 4 + wv) * 64 + lane;        // slot 0..2047
      int m = s >> 4;                          // row
      int lc = (s & 15) ^ (m & 15);            // logical chunk
      GLL16(A + (size_t)(m0 + m) * K + k0 + (lc << 3), &As[buf][(i * 4 + wv) * 512]);
    }
#pragma unroll
    for (int i = 0; i < 8; i++){
      int s = (i * 4 + wv) * 64 + lane;
      int n = s >> 4;
      int lc = (s & 15) ^ (n & 15);
      GLL16(Bt + (size_t)(n0 + n) * K + k0 + (lc << 3), &Bs[buf][(i * 4 + wv) * 512]);
    }
  };

  f32x4 acc[4][4] = {};
  STAGE(0, 0);
  STAGE(1, 1);

  for (int kt = 0; kt < KT; kt++){
    if (kt < KT - 1) asm volatile("s_waitcnt vmcnt(16)" ::: "memory");
    else             asm volatile("s_waitcnt vmcnt(0)" ::: "memory");
    SCHEDB; BARRIER; SCHEDB;
    const u16* Asc = &As[kt & 1][0];
    const u16* Bsc = &Bs[kt & 1][0];
#pragma unroll
    for (int h = 0; h < 4; h++){               // 4 k-steps of 32
      short8 af[4], bfr[4];
#pragma unroll
      for (int mi = 0; mi < 4; mi++){
        int m = wm * 64 + mi * 16 + l15;
        af[mi] = *(const short8*)(Asc + m * 128 + (((h * 4 + g) ^ (m & 15)) << 3));
      }
#pragma unroll
      for (int ni = 0; ni < 4; ni++){
        int n = wn * 64 + ni * 16 + l15;
        bfr[ni] = *(const short8*)(Bsc + n * 128 + (((h * 4 + g) ^ (n & 15)) << 3));
      }
      __builtin_amdgcn_s_setprio(1);
#pragma unroll
      for (int mi = 0; mi < 4; mi++)
#pragma unroll
        for (int ni = 0; ni < 4; ni++)
          acc[mi][ni] = __builtin_amdgcn_mfma_f32_16x16x32_bf16(af[mi], bfr[ni], acc[mi][ni], 0, 0, 0);
      __builtin_amdgcn_s_setprio(0);
    }
    asm volatile("s_waitcnt lgkmcnt(0)" ::: "memory");
    SCHEDB; BARRIER; SCHEDB;
    if (kt + 2 < KT) STAGE(kt & 1, kt + 2);
  }

#pragma unroll
  for (int mi = 0; mi < 4; mi++){
#pragma unroll
    for (int ni = 0; ni < 4; ni++){
      int col = n0 + wn * 64 + ni * 16 + l15;
#pragma unroll
      for (int r = 0; r < 4; r++){
        int row = m0 + wm * 64 + mi * 16 + g * 4 + r;
        outf[(size_t)row * N + col] = acc[mi][ni][r];
      }
    }
  }
}

// ---------------- flash block-causal attention (R10 schedule, log2 softmax) ----------------
__global__ __launch_bounds__(512, 4) void k_attn(const u16* __restrict__ qkv2,
                                                 const u16* __restrict__ vt2,
                                                 u16* __restrict__ ao){
  __shared__ u16 Ks[2][8192];   // [kv=128][hd=64] per buf, XOR-swizzled chunks (32KB)
  __shared__ u16 Vs[8192];      // [d=64][kv=128], XOR-swizzled chunks (16KB)
  __shared__ u16 Ps[8][1024];   // per-wave P half [16q][64kv], swizzle ^((q&7)<<4) (16KB)

  int bid = blockIdx.x;
  int bh = bid & 31;                          // bid%8 stable -> same-bh on same XCD
  int idx = (bid >> 5) & 7;
  int half = bid >> 8;
  int qb = half ? idx : 15 - idx;
  int b = bh >> 4, h = bh & 15;
  int t = threadIdx.x, wv = t >> 6, lane = t & 63, l15 = lane & 15, g = lane >> 4;

  int qrow = qb * 128 + wv * 16 + l15;
  const u16* qp = qkv2 + (size_t)(b * N_ + qrow) * NQK_ + h * 64 + g * 8;
  short8 qfa = *(const short8*)qp;        // roped + (1/8)*log2e-scaled by gemm1
  short8 qfb = *(const short8*)(qp + 32);

  char* Pw = (char*)&Ps[wv][0];
  const u16* vb_ = vt2 + (size_t)bh * 4096 * 32;   // vt2[bh][nc][d][32]

  auto STAGE_K = [&](int buf, int j) {
#pragma unroll
    for (int i = 0; i < 2; i++){
      int c = (i * 8 + wv) * 64 + lane;
      int kv = c >> 3, pos = c & 7;
      GLL16(qkv2 + (size_t)(b * N_ + j * 128 + kv) * NQK_ + DIM_ + h * 64 + ((pos ^ (kv & 7)) << 3),
            &Ks[buf][(i * 8 + wv) * 512]);
    }
  };
  auto STAGE_V = [&](int j) {
#pragma unroll
    for (int i = 0; i < 2; i++){
      int c = (wv * 2 + i) * 64 + lane;
      int d = c >> 4;
      int lc = (c & 15) ^ (d & 7);
      GLL16(vb_ + ((size_t)((j * 4 + (lc >> 2)) * 64 + d) * 32) + ((lc & 3) << 3),
            &Vs[(wv * 2 + i) * 512]);
    }
  };

  f32x4 oacc[4] = {};
  float m_run = -INFINITY, l_run = 0.0f;

  STAGE_K(0, 0);
  __syncthreads();
  int cur = 0;

  for (int j = 0; j <= qb; j++){
    STAGE_V(j);                                // issues 2 loads (oldest)
    if (j < qb) STAGE_K(cur ^ 1, j + 1);       // issues 2 more (newest)
    const u16* K = &Ks[cur][0];

    f32x4 sv[8];
    __builtin_amdgcn_s_setprio(1);
#pragma unroll
    for (int s = 0; s < 8; s++){
      int kvr = s * 16 + l15;
      short8 kf0 = *(const short8*)(K + kvr * 64 + ((g ^ (kvr & 7)) << 3));
      short8 kf1 = *(const short8*)(K + kvr * 64 + (((4 + g) ^ (kvr & 7)) << 3));
      f32x4 z = {0.f, 0.f, 0.f, 0.f};
      z = __builtin_amdgcn_mfma_f32_16x16x32_bf16(kf0, qfa, z, 0, 0, 0);
      z = __builtin_amdgcn_mfma_f32_16x16x32_bf16(kf1, qfb, z, 0, 0, 0);
      sv[s] = z;
    }
    __builtin_amdgcn_s_setprio(0);

    // online softmax in log2 domain; max via v_max3-fusable pairs (16-op chain)
    float mt = fmaxf(sv[0][0], sv[0][1]);
    mt = fmaxf(fmaxf(sv[0][2], sv[0][3]), mt);
#pragma unroll
    for (int s = 1; s < 8; s++){
      mt = fmaxf(fmaxf(sv[s][0], sv[s][1]), mt);
      mt = fmaxf(fmaxf(sv[s][2], sv[s][3]), mt);
    }
    mt = fmaxf(mt, __shfl_xor(mt, 16, 64));
    mt = fmaxf(mt, __shfl_xor(mt, 32, 64));
    if (!__all(mt <= m_run + 11.5415603f)){    // defer-max THR = 8*log2(e)
      float m_new = fmaxf(m_run, mt);
      float alpha = exp2f(m_run - m_new);
      float af4[4];
#pragma unroll
      for (int r = 0; r < 4; r++) af4[r] = __shfl(alpha, g * 4 + r, 64);
#pragma unroll
      for (int ni = 0; ni < 4; ni++)
#pragma unroll
        for (int r = 0; r < 4; r++) oacc[ni][r] *= af4[r];
      l_run *= alpha;
      m_run = m_new;
    }
    float psum = 0.0f;
#pragma unroll
    for (int s = 0; s < 8; s++)
#pragma unroll
      for (int r = 0; r < 4; r++){
        float p = exp2f(sv[s][r] - m_run);
        sv[s][r] = p;
        psum += p;
      }
    psum += __shfl_xor(psum, 16, 64);
    psum += __shfl_xor(psum, 32, 64);
    l_run += psum;

    // V(j) landed (own oldest 2 loads); K(j+1) stays in flight through PV
    if (j < qb) asm volatile("s_waitcnt vmcnt(2)" ::: "memory");
    else        asm volatile("s_waitcnt vmcnt(0)" ::: "memory");
    SCHEDB; BARRIER; SCHEDB;

#pragma unroll
    for (int hf = 0; hf < 2; hf++){
#pragma unroll
      for (int s2 = 0; s2 < 4; s2++){
        int s = hf * 4 + s2;
        uint2 pk;
        pk.x = cvtpk(sv[s][0], sv[s][1]);
        pk.y = cvtpk(sv[s][2], sv[s][3]);
        int byte = (l15 * 128 + s2 * 32 + g * 8) ^ ((l15 & 7) << 4);
        *(uint2*)(Pw + byte) = pk;
      }
      __builtin_amdgcn_s_setprio(1);
#pragma unroll
      for (int cc2 = 0; cc2 < 2; cc2++){
        int cc = hf * 2 + cc2;
        int rb = (l15 * 128 + cc2 * 64 + g * 16) ^ ((l15 & 7) << 4);
        short8 pa = *(const short8*)(Pw + rb);
#pragma unroll
        for (int ni = 0; ni < 4; ni++){
          int d = ni * 16 + l15;
          short8 vf = *(const short8*)(Vs + d * 128 + (((cc * 4 + g) ^ (d & 7)) << 3));
          oacc[ni] = __builtin_amdgcn_mfma_f32_16x16x32_bf16(pa, vf, oacc[ni], 0, 0, 0);
        }
      }
      __builtin_amdgcn_s_setprio(0);
    }

    __syncthreads();   // all waves done with Vs / Ks[cur]; K(j+1) drained (flew full tile)
    cur ^= 1;
  }

  float lf[4];
#pragma unroll
  for (int r = 0; r < 4; r++) lf[r] = 1.0f / __shfl(l_run, g * 4 + r, 64);
#pragma unroll
  for (int ni = 0; ni < 4; ni++)
#pragma unroll
    for (int r = 0; r < 4; r++){
      size_t idxo = (size_t)(b * N_ + qb * 128 + wv * 16 + g * 4 + r) * DIM_ + h * 64 + ni * 16 + l15;
      ao[idxo] = f2bf(oacc[ni][r] * lf[r]);
    }
}

// ---------------- launch ----------------
extern "C" void kernel_launch(void* const* d_in, const int* in_sizes, int n_in,
                              void* d_out, int out_size, void* d_ws, size_t ws_size,
                              hipStream_t stream){
  const float* x      = (const float*)d_in[0];
  const float* norm_w = (const float*)d_in[1];
  const float* w_qkv  = (const float*)d_in[2];
  const float* w_out  = (const float*)d_in[3];
  float* out0 = (float*)d_out;                      // [B,N,DIM] fp32
  float* out1 = out0 + (size_t)NR_ * DIM_;          // orig_v [B,H,N,DH] fp32

  char* ws = (char*)d_ws;
  u16* xn    = (u16*)(ws + 0);           // 8 MB (reused as attn-out after GEMM1)
  u16* wqkvT = (u16*)(ws + 8388608);     // 6 MB
  u16* woutT = (u16*)(ws + 14680064);    // 2 MB
  u16* qkv2  = (u16*)(ws + 16777216);    // 16 MB  [row][2048] roped q|k bf16
  u16* vt2   = (u16*)(ws + 33554432);    // 8 MB   [bh][64][64][32] bf16
  float2* cs = (float2*)(ws + 41943040); // 0.5 MB
  u16* ao    = xn;                       // alias: xn dead after GEMM1

  k_rmsnorm<<<NR_, 256, 0, stream>>>(x, norm_w, xn);
  k_prep<<<1280, 256, 0, stream>>>(w_qkv, w_out, wqkvT, woutT, cs);
  k_gemm1<<<512, 256, 0, stream>>>(xn, wqkvT, qkv2, out1, vt2, cs);
  k_attn<<<512, 512, 0, stream>>>(qkv2, vt2, ao);
  k_gemm2<<<256, 256, 0, stream>>>(ao, woutT, out0);
}

// Round 17
// 118.090 us; speedup vs baseline: 1.1452x; 1.0409x over previous
//
#include <hip/hip_runtime.h>
#include <stdint.h>

#define B_    2
#define N_    2048
#define DIM_  1024
#define H_    16
#define DH_   64
#define NR_   4096     // B*N rows
#define NQKV_ 3072
#define NQK_  2048     // q,k columns kept in qkv2

typedef unsigned short u16;
typedef __attribute__((ext_vector_type(8))) short short8;
typedef __attribute__((ext_vector_type(4))) float f32x4;

static __device__ __forceinline__ u16 f2bf(float f){
  union { float f; uint32_t u; } x; x.f = f;
  return (u16)((x.u + 0x7fffu + ((x.u >> 16) & 1u)) >> 16);
}
static __device__ __forceinline__ float bf2f(uint32_t b){
  union { uint32_t u; float f; } x; x.u = b << 16;
  return x.f;
}
// hardware packed f32->bf16 (RNE): D = {lo: bf16(a), hi: bf16(b)}
static __device__ __forceinline__ uint32_t cvtpk(float a, float b){
  uint32_t r;
  asm("v_cvt_pk_bf16_f32 %0, %1, %2" : "=v"(r) : "v"(a), "v"(b));
  return r;
}

// global -> LDS direct copy, 16B per lane; LDS dest is wave-uniform base + lane*16
#define GLL16(gp, lp) __builtin_amdgcn_global_load_lds( \
    (const __attribute__((address_space(1))) void*)(gp), \
    (__attribute__((address_space(3))) void*)(lp), 16, 0, 0)

#define SCHEDB __builtin_amdgcn_sched_barrier(0)
#define BARRIER __builtin_amdgcn_s_barrier()

// ---------------- fused prep: RMSNorm + both weight transposes + cos/sin ----------------
static __device__ __forceinline__ void tcast_body(const float* __restrict__ src,
                                                  u16* __restrict__ dst,
                                                  int R, int C, int c0, int r0, int t,
                                                  float (*ls)[65]){
  int rr = t >> 2, q = t & 3;
  const float* s = src + (size_t)(r0 + rr) * C + c0 + q * 16;
#pragma unroll
  for (int j = 0; j < 4; j++){
    float4 v = ((const float4*)s)[j];
    ls[rr][q*16 + j*4 + 0] = v.x;
    ls[rr][q*16 + j*4 + 1] = v.y;
    ls[rr][q*16 + j*4 + 2] = v.z;
    ls[rr][q*16 + j*4 + 3] = v.w;
  }
  __syncthreads();
  int cc = t >> 2;
  union { u16 u[16]; uint4 v4[2]; } o;
#pragma unroll
  for (int i = 0; i < 16; i++) o.u[i] = f2bf(ls[q*16 + i][cc]);
  u16* d = dst + (size_t)(c0 + cc) * R + r0 + q * 16;
  ((uint4*)d)[0] = o.v4[0];
  ((uint4*)d)[1] = o.v4[1];
}

__global__ __launch_bounds__(256) void k_prep(const float* __restrict__ x,
                                              const float* __restrict__ norm_w,
                                              u16* __restrict__ xn,
                                              const float* __restrict__ w_qkv,
                                              const float* __restrict__ w_out,
                                              u16* __restrict__ wqkvT,
                                              u16* __restrict__ woutT,
                                              float2* __restrict__ cs){
  __shared__ float ls[64][65];
  int bid = blockIdx.x;
  int t = threadIdx.x;
  if (bid < 4096){
    // RMSNorm row bid + cast to bf16
    int row = bid;
    float4 v = ((const float4*)(x + (size_t)row * DIM_))[t];
    float ss = v.x*v.x + v.y*v.y + v.z*v.z + v.w*v.w;
#pragma unroll
    for (int m = 1; m < 64; m <<= 1) ss += __shfl_xor(ss, m, 64);
    float* red = &ls[0][0];
    if ((t & 63) == 0) red[t >> 6] = ss;
    __syncthreads();
    float tot = red[0] + red[1] + red[2] + red[3];
    float r = rsqrtf(tot * (1.0f / DIM_) + 1.1920929e-07f);
    float4 wv = ((const float4*)norm_w)[t];
    union { u16 u[4]; uint2 v2; } o;
    o.u[0] = f2bf(v.x * r * wv.x);
    o.u[1] = f2bf(v.y * r * wv.y);
    o.u[2] = f2bf(v.z * r * wv.z);
    o.u[3] = f2bf(v.w * r * wv.w);
    ((uint2*)(xn + (size_t)row * DIM_))[t] = o.v2;
  } else if (bid < 4864){
    // w_qkv [1024][3072] -> wqkvT [3072][1024]
    int idx = bid - 4096;
    tcast_body(w_qkv, wqkvT, DIM_, NQKV_, (idx % 48) * 64, (idx / 48) * 64, t, ls);
  } else if (bid < 5120){
    // w_out [1024][1024] -> woutT [1024][1024]
    int idx = bid - 4864;
    tcast_body(w_out, woutT, DIM_, DIM_, (idx & 15) * 64, (idx >> 4) * 64, t, ls);
  } else {
    int tid = (bid - 5120) * 256 + t;          // 65536 = N_*32
    int n = tid >> 5, i = tid & 31;
    float inv = powf(10000.0f, -(float)(2 * i) * (1.0f / 64.0f));
    float a = (float)n * inv;
    cs[tid] = make_float2(cosf(a), sinf(a));
  }
}

// ---------------- GEMM1: 128x192 tile, BK=64, counted-vmcnt, grid 512 (R13) ----------------
// C[4096,3072] = xn @ wqkvT^T. Epilogue: cols<2048 -> fused interleaved RoPE
// (q scaled by 0.125*log2e -> log2-domain scores) -> bf16 qkv2;
// cols>=2048 -> fp32 orig_v + bf16 vT2 tiled.
__global__ __launch_bounds__(256, 2) void k_gemm1(const u16* __restrict__ A,
                                                  const u16* __restrict__ Bt,
                                                  u16* __restrict__ outb,
                                                  float* __restrict__ outf,
                                                  u16* __restrict__ vt2,
                                                  const float2* __restrict__ cs){
  __shared__ u16 As[2][8192];    // [128 m][64 k] per buf, chunk-XOR swizzle (32KB)
  __shared__ u16 Bs[2][12288];   // [192 n][64 k] per buf (48KB)
  const int K = 1024, KT = 16;

  int xcd = blockIdx.x & 7, c = blockIdx.x >> 3;       // c in 0..63
  int m0 = ((xcd >> 1) * 8 + (c >> 3)) << 7;           // m-panel 0..31 (128 rows)
  int n0 = ((xcd & 1) * 8 + (c & 7)) * 192;            // n-panel 0..15 (192 cols)

  int t = threadIdx.x, wv = t >> 6, lane = t & 63, l15 = lane & 15, g = lane >> 4;
  int wm = wv >> 1, wn = wv & 1;

  auto STAGE = [&](int buf, int kt){
    int k0 = kt << 6;
#pragma unroll
    for (int i = 0; i < 4; i++){           // A: 128 rows x 64 k = 16KB
      int cc = (i * 4 + wv) * 64 + lane;
      int m = cc >> 3, pos = cc & 7;
      GLL16(A + (size_t)(m0 + m) * K + k0 + ((pos ^ (m & 7)) << 3), &As[buf][(i * 4 + wv) * 512]);
    }
#pragma unroll
    for (int i = 0; i < 6; i++){           // B: 192 rows x 64 k = 24KB
      int cc = (i * 4 + wv) * 64 + lane;
      int n = cc >> 3, pos = cc & 7;
      GLL16(Bt + (size_t)(n0 + n) * K + k0 + ((pos ^ (n & 7)) << 3), &Bs[buf][(i * 4 + wv) * 512]);
    }
  };

  f32x4 acc[4][6] = {};
  STAGE(0, 0);
  STAGE(1, 1);

  for (int kt = 0; kt < KT; kt++){
    if (kt < KT - 1) asm volatile("s_waitcnt vmcnt(10)" ::: "memory");
    else             asm volatile("s_waitcnt vmcnt(0)" ::: "memory");
    SCHEDB; BARRIER; SCHEDB;
    const u16* Asc = &As[kt & 1][0];
    const u16* Bsc = &Bs[kt & 1][0];
#pragma unroll
    for (int h = 0; h < 2; h++){
      short8 af[4], bfr[6];
#pragma unroll
      for (int mi = 0; mi < 4; mi++){
        int m = wm * 64 + mi * 16 + l15;
        af[mi] = *(const short8*)(Asc + m * 64 + (((h * 4 + g) ^ (m & 7)) << 3));
      }
#pragma unroll
      for (int ni = 0; ni < 6; ni++){
        int n = wn * 96 + ni * 16 + l15;
        bfr[ni] = *(const short8*)(Bsc + n * 64 + (((h * 4 + g) ^ (n & 7)) << 3));
      }
      __builtin_amdgcn_s_setprio(1);
#pragma unroll
      for (int mi = 0; mi < 4; mi++)
#pragma unroll
        for (int ni = 0; ni < 6; ni++)
          acc[mi][ni] = __builtin_amdgcn_mfma_f32_16x16x32_bf16(af[mi], bfr[ni], acc[mi][ni], 0, 0, 0);
      __builtin_amdgcn_s_setprio(0);
    }
    asm volatile("s_waitcnt lgkmcnt(0)" ::: "memory");
    SCHEDB; BARRIER; SCHEDB;
    if (kt + 2 < KT) STAGE(kt & 1, kt + 2);
  }

#pragma unroll
  for (int mi = 0; mi < 4; mi++){
#pragma unroll
    for (int ni = 0; ni < 6; ni++){
      int col = n0 + wn * 96 + ni * 16 + l15;
#pragma unroll
      for (int r = 0; r < 4; r++){
        int row = m0 + wm * 64 + mi * 16 + g * 4 + r;
        float val = acc[mi][ni][r];
        if (col < NQK_){
          // fused interleaved RoPE: partner element lives in adjacent lane
          int n = row & (N_ - 1);
          int dpair = (col & 63) >> 1;
          float2 cv = cs[(size_t)n * 32 + dpair];
          float partner = __shfl_xor(val, 1, 64);
          float y = (l15 & 1) ? (val * cv.x + partner * cv.y)
                              : (val * cv.x - partner * cv.y);
          if (col < DIM_) y *= 0.18033688f;   // (1/8)*log2(e): log2-domain scores
          outb[(size_t)row * NQK_ + col] = f2bf(y);
        } else {
          int hh = (col - 2 * DIM_) >> 6, d = col & 63;
          int b = row >> 11, n = row & (N_ - 1);
          outf[((size_t)((b * H_ + hh) * N_ + n) << 6) + d] = val;
          // vT2 tiled: [bh][n>>5][d][n&31]
          vt2[((size_t)((b * H_ + hh) * 64 + (n >> 5)) * 64 + d) * 32 + (n & 31)] = f2bf(val);
        }
      }
    }
  }
}

// ---------------- GEMM2: 128x128 tile, BK=128, counted-vmcnt, grid 256 ----------------
__global__ __launch_bounds__(256) void k_gemm2(const u16* __restrict__ A,
                                               const u16* __restrict__ Bt,
                                               float* __restrict__ outf){
  __shared__ u16 As[2][16384];   // [128 m][128 k] per buf (32KB each)
  __shared__ u16 Bs[2][16384];   // [128 n][128 k] per buf (32KB each)
  const int K = 1024, KT = 8, N = 1024;

  int xcd = blockIdx.x & 7, c = blockIdx.x >> 3;       // c in 0..31
  int m0 = (xcd * 4 + (c >> 3)) << 7;
  int n0 = (c & 7) << 7;

  int t = threadIdx.x, wv = t >> 6, lane = t & 63, l15 = lane & 15, g = lane >> 4;
  int wm = wv >> 1, wn = wv & 1;

  auto STAGE = [&](int buf, int kt){
    int k0 = kt << 7;
#pragma unroll
    for (int i = 0; i < 8; i++){
      int s = (i * 4 + wv) * 64 + lane;        // slot 0..2047
      int m = s >> 4;                          // row
      int lc = (s & 15) ^ (m & 15);            // logical chunk
      GLL16(A + (size_t)(m0 + m) * K + k0 + (lc << 3), &As[buf][(i * 4 + wv) * 512]);
    }
#pragma unroll
    for (int i = 0; i < 8; i++){
      int s = (i * 4 + wv) * 64 + lane;
      int n = s >> 4;
      int lc = (s & 15) ^ (n & 15);
      GLL16(Bt + (size_t)(n0 + n) * K + k0 + (lc << 3), &Bs[buf][(i * 4 + wv) * 512]);
    }
  };

  f32x4 acc[4][4] = {};
  STAGE(0, 0);
  STAGE(1, 1);

  for (int kt = 0; kt < KT; kt++){
    if (kt < KT - 1) asm volatile("s_waitcnt vmcnt(16)" ::: "memory");
    else             asm volatile("s_waitcnt vmcnt(0)" ::: "memory");
    SCHEDB; BARRIER; SCHEDB;
    const u16* Asc = &As[kt & 1][0];
    const u16* Bsc = &Bs[kt & 1][0];
#pragma unroll
    for (int h = 0; h < 4; h++){               // 4 k-steps of 32
      short8 af[4], bfr[4];
#pragma unroll
      for (int mi = 0; mi < 4; mi++){
        int m = wm * 64 + mi * 16 + l15;
        af[mi] = *(const short8*)(Asc + m * 128 + (((h * 4 + g) ^ (m & 15)) << 3));
      }
#pragma unroll
      for (int ni = 0; ni < 4; ni++){
        int n = wn * 64 + ni * 16 + l15;
        bfr[ni] = *(const short8*)(Bsc + n * 128 + (((h * 4 + g) ^ (n & 15)) << 3));
      }
      __builtin_amdgcn_s_setprio(1);
#pragma unroll
      for (int mi = 0; mi < 4; mi++)
#pragma unroll
        for (int ni = 0; ni < 4; ni++)
          acc[mi][ni] = __builtin_amdgcn_mfma_f32_16x16x32_bf16(af[mi], bfr[ni], acc[mi][ni], 0, 0, 0);
      __builtin_amdgcn_s_setprio(0);
    }
    asm volatile("s_waitcnt lgkmcnt(0)" ::: "memory");
    SCHEDB; BARRIER; SCHEDB;
    if (kt + 2 < KT) STAGE(kt & 1, kt + 2);
  }

#pragma unroll
  for (int mi = 0; mi < 4; mi++){
#pragma unroll
    for (int ni = 0; ni < 4; ni++){
      int col = n0 + wn * 64 + ni * 16 + l15;
#pragma unroll
      for (int r = 0; r < 4; r++){
        int row = m0 + wm * 64 + mi * 16 + g * 4 + r;
        outf[(size_t)row * N + col] = acc[mi][ni][r];
      }
    }
  }
}

// ---------------- flash block-causal attention (R10 schedule, log2 softmax) ----------------
// Softmax denominator via MFMA against all-ones B-fragment: lacc[r] accumulates
// row-sums of bf16 P in the same register layout as oacc (no shuffles).
__global__ __launch_bounds__(512, 4) void k_attn(const u16* __restrict__ qkv2,
                                                 const u16* __restrict__ vt2,
                                                 u16* __restrict__ ao){
  __shared__ u16 Ks[2][8192];   // [kv=128][hd=64] per buf, XOR-swizzled chunks (32KB)
  __shared__ u16 Vs[8192];      // [d=64][kv=128], XOR-swizzled chunks (16KB)
  __shared__ u16 Ps[8][1024];   // per-wave P half [16q][64kv], swizzle ^((q&7)<<4) (16KB)

  int bid = blockIdx.x;
  int bh = bid & 31;                          // bid%8 stable -> same-bh on same XCD
  int idx = (bid >> 5) & 7;
  int half = bid >> 8;
  int qb = half ? idx : 15 - idx;
  int b = bh >> 4, h = bh & 15;
  int t = threadIdx.x, wv = t >> 6, lane = t & 63, l15 = lane & 15, g = lane >> 4;

  int qrow = qb * 128 + wv * 16 + l15;
  const u16* qp = qkv2 + (size_t)(b * N_ + qrow) * NQK_ + h * 64 + g * 8;
  short8 qfa = *(const short8*)qp;        // roped + (1/8)*log2e-scaled by gemm1
  short8 qfb = *(const short8*)(qp + 32);

  union { u16 u[8]; short8 s; } one_;
#pragma unroll
  for (int i = 0; i < 8; i++) one_.u[i] = 0x3F80;   // bf16 1.0
  const short8 onesf = one_.s;

  char* Pw = (char*)&Ps[wv][0];
  const u16* vb_ = vt2 + (size_t)bh * 4096 * 32;   // vt2[bh][nc][d][32]

  auto STAGE_K = [&](int buf, int j) {
#pragma unroll
    for (int i = 0; i < 2; i++){
      int c = (i * 8 + wv) * 64 + lane;
      int kv = c >> 3, pos = c & 7;
      GLL16(qkv2 + (size_t)(b * N_ + j * 128 + kv) * NQK_ + DIM_ + h * 64 + ((pos ^ (kv & 7)) << 3),
            &Ks[buf][(i * 8 + wv) * 512]);
    }
  };
  auto STAGE_V = [&](int j) {
#pragma unroll
    for (int i = 0; i < 2; i++){
      int c = (wv * 2 + i) * 64 + lane;
      int d = c >> 4;
      int lc = (c & 15) ^ (d & 7);
      GLL16(vb_ + ((size_t)((j * 4 + (lc >> 2)) * 64 + d) * 32) + ((lc & 3) << 3),
            &Vs[(wv * 2 + i) * 512]);
    }
  };

  f32x4 oacc[4] = {};
  f32x4 lacc = {};
  float m_run = -INFINITY;

  STAGE_K(0, 0);
  __syncthreads();
  int cur = 0;

  for (int j = 0; j <= qb; j++){
    STAGE_V(j);                                // issues 2 loads (oldest)
    if (j < qb) STAGE_K(cur ^ 1, j + 1);       // issues 2 more (newest)
    const u16* K = &Ks[cur][0];

    f32x4 sv[8];
    __builtin_amdgcn_s_setprio(1);
#pragma unroll
    for (int s = 0; s < 8; s++){
      int kvr = s * 16 + l15;
      short8 kf0 = *(const short8*)(K + kvr * 64 + ((g ^ (kvr & 7)) << 3));
      short8 kf1 = *(const short8*)(K + kvr * 64 + (((4 + g) ^ (kvr & 7)) << 3));
      f32x4 z = {0.f, 0.f, 0.f, 0.f};
      z = __builtin_amdgcn_mfma_f32_16x16x32_bf16(kf0, qfa, z, 0, 0, 0);
      z = __builtin_amdgcn_mfma_f32_16x16x32_bf16(kf1, qfb, z, 0, 0, 0);
      sv[s] = z;
    }
    __builtin_amdgcn_s_setprio(0);

    // online softmax in log2 domain; max via v_max3-fusable pairs (16-op chain)
    float mt = fmaxf(sv[0][0], sv[0][1]);
    mt = fmaxf(fmaxf(sv[0][2], sv[0][3]), mt);
#pragma unroll
    for (int s = 1; s < 8; s++){
      mt = fmaxf(fmaxf(sv[s][0], sv[s][1]), mt);
      mt = fmaxf(fmaxf(sv[s][2], sv[s][3]), mt);
    }
    mt = fmaxf(mt, __shfl_xor(mt, 16, 64));
    mt = fmaxf(mt, __shfl_xor(mt, 32, 64));
    if (!__all(mt <= m_run + 11.5415603f)){    // defer-max THR = 8*log2(e)
      float m_new = fmaxf(m_run, mt);
      float alpha = exp2f(m_run - m_new);
      float af4[4];
#pragma unroll
      for (int r = 0; r < 4; r++) af4[r] = __shfl(alpha, g * 4 + r, 64);
#pragma unroll
      for (int r = 0; r < 4; r++){
#pragma unroll
        for (int ni = 0; ni < 4; ni++) oacc[ni][r] *= af4[r];
        lacc[r] *= af4[r];
      }
      m_run = m_new;
    }
#pragma unroll
    for (int s = 0; s < 8; s++)
#pragma unroll
      for (int r = 0; r < 4; r++)
        sv[s][r] = exp2f(sv[s][r] - m_run);

    // V(j) landed (own oldest 2 loads); K(j+1) stays in flight through PV
    if (j < qb) asm volatile("s_waitcnt vmcnt(2)" ::: "memory");
    else        asm volatile("s_waitcnt vmcnt(0)" ::: "memory");
    SCHEDB; BARRIER; SCHEDB;

#pragma unroll
    for (int hf = 0; hf < 2; hf++){
#pragma unroll
      for (int s2 = 0; s2 < 4; s2++){
        int s = hf * 4 + s2;
        uint2 pk;
        pk.x = cvtpk(sv[s][0], sv[s][1]);
        pk.y = cvtpk(sv[s][2], sv[s][3]);
        int byte = (l15 * 128 + s2 * 32 + g * 8) ^ ((l15 & 7) << 4);
        *(uint2*)(Pw + byte) = pk;
      }
      __builtin_amdgcn_s_setprio(1);
#pragma unroll
      for (int cc2 = 0; cc2 < 2; cc2++){
        int cc = hf * 2 + cc2;
        int rb = (l15 * 128 + cc2 * 64 + g * 16) ^ ((l15 & 7) << 4);
        short8 pa = *(const short8*)(Pw + rb);
#pragma unroll
        for (int ni = 0; ni < 4; ni++){
          int d = ni * 16 + l15;
          short8 vf = *(const short8*)(Vs + d * 128 + (((cc * 4 + g) ^ (d & 7)) << 3));
          oacc[ni] = __builtin_amdgcn_mfma_f32_16x16x32_bf16(pa, vf, oacc[ni], 0, 0, 0);
        }
        lacc = __builtin_amdgcn_mfma_f32_16x16x32_bf16(pa, onesf, lacc, 0, 0, 0);
      }
      __builtin_amdgcn_s_setprio(0);
    }

    __syncthreads();   // all waves done with Vs / Ks[cur]; K(j+1) drained (flew full tile)
    cur ^= 1;
  }

#pragma unroll
  for (int ni = 0; ni < 4; ni++)
#pragma unroll
    for (int r = 0; r < 4; r++){
      size_t idxo = (size_t)(b * N_ + qb * 128 + wv * 16 + g * 4 + r) * DIM_ + h * 64 + ni * 16 + l15;
      ao[idxo] = f2bf(oacc[ni][r] / lacc[r]);
    }
}

// ---------------- launch ----------------
extern "C" void kernel_launch(void* const* d_in, const int* in_sizes, int n_in,
                              void* d_out, int out_size, void* d_ws, size_t ws_size,
                              hipStream_t stream){
  const float* x      = (const float*)d_in[0];
  const float* norm_w = (const float*)d_in[1];
  const float* w_qkv  = (const float*)d_in[2];
  const float* w_out  = (const float*)d_in[3];
  float* out0 = (float*)d_out;                      // [B,N,DIM] fp32
  float* out1 = out0 + (size_t)NR_ * DIM_;          // orig_v [B,H,N,DH] fp32

  char* ws = (char*)d_ws;
  u16* xn    = (u16*)(ws + 0);           // 8 MB (reused as attn-out after GEMM1)
  u16* wqkvT = (u16*)(ws + 8388608);     // 6 MB
  u16* woutT = (u16*)(ws + 14680064);    // 2 MB
  u16* qkv2  = (u16*)(ws + 16777216);    // 16 MB  [row][2048] roped q|k bf16
  u16* vt2   = (u16*)(ws + 33554432);    // 8 MB   [bh][64][64][32] bf16
  float2* cs = (float2*)(ws + 41943040); // 0.5 MB
  u16* ao    = xn;                       // alias: xn dead after GEMM1

  k_prep<<<5376, 256, 0, stream>>>(x, norm_w, xn, w_qkv, w_out, wqkvT, woutT, cs);
  k_gemm1<<<512, 256, 0, stream>>>(xn, wqkvT, qkv2, out1, vt2, cs);
  k_attn<<<512, 512, 0, stream>>>(qkv2, vt2, ao);
  k_gemm2<<<256, 256, 0, stream>>>(ao, woutT, out0);
}

// Round 18
// 116.745 us; speedup vs baseline: 1.1584x; 1.0115x over previous
//
#include <hip/hip_runtime.h>
#include <stdint.h>

#define B_    2
#define N_    2048
#define DIM_  1024
#define H_    16
#define DH_   64
#define NR_   4096     // B*N rows
#define NQKV_ 3072
#define NQK_  2048     // q,k columns kept in qkv2

typedef unsigned short u16;
typedef __attribute__((ext_vector_type(8))) short short8;
typedef __attribute__((ext_vector_type(4))) float f32x4;

static __device__ __forceinline__ u16 f2bf(float f){
  union { float f; uint32_t u; } x; x.f = f;
  return (u16)((x.u + 0x7fffu + ((x.u >> 16) & 1u)) >> 16);
}
static __device__ __forceinline__ float bf2f(uint32_t b){
  union { uint32_t u; float f; } x; x.u = b << 16;
  return x.f;
}
// hardware packed f32->bf16 (RNE): D = {lo: bf16(a), hi: bf16(b)}
static __device__ __forceinline__ uint32_t cvtpk(float a, float b){
  uint32_t r;
  asm("v_cvt_pk_bf16_f32 %0, %1, %2" : "=v"(r) : "v"(a), "v"(b));
  return r;
}

// global -> LDS direct copy, 16B per lane; LDS dest is wave-uniform base + lane*16
#define GLL16(gp, lp) __builtin_amdgcn_global_load_lds( \
    (const __attribute__((address_space(1))) void*)(gp), \
    (__attribute__((address_space(3))) void*)(lp), 16, 0, 0)

#define SCHEDB __builtin_amdgcn_sched_barrier(0)
#define BARRIER __builtin_amdgcn_s_barrier()

// ---------------- fused prep: RMSNorm + both weight transposes + cos/sin ----------------
static __device__ __forceinline__ void tcast_body(const float* __restrict__ src,
                                                  u16* __restrict__ dst,
                                                  int R, int C, int c0, int r0, int t,
                                                  float (*ls)[65]){
  int rr = t >> 2, q = t & 3;
  const float* s = src + (size_t)(r0 + rr) * C + c0 + q * 16;
#pragma unroll
  for (int j = 0; j < 4; j++){
    float4 v = ((const float4*)s)[j];
    ls[rr][q*16 + j*4 + 0] = v.x;
    ls[rr][q*16 + j*4 + 1] = v.y;
    ls[rr][q*16 + j*4 + 2] = v.z;
    ls[rr][q*16 + j*4 + 3] = v.w;
  }
  __syncthreads();
  int cc = t >> 2;
  union { u16 u[16]; uint4 v4[2]; } o;
#pragma unroll
  for (int i = 0; i < 16; i++) o.u[i] = f2bf(ls[q*16 + i][cc]);
  u16* d = dst + (size_t)(c0 + cc) * R + r0 + q * 16;
  ((uint4*)d)[0] = o.v4[0];
  ((uint4*)d)[1] = o.v4[1];
}

__global__ __launch_bounds__(256) void k_prep(const float* __restrict__ x,
                                              const float* __restrict__ norm_w,
                                              u16* __restrict__ xn,
                                              const float* __restrict__ w_qkv,
                                              const float* __restrict__ w_out,
                                              u16* __restrict__ wqkvT,
                                              u16* __restrict__ woutT,
                                              float2* __restrict__ cs){
  __shared__ float ls[64][65];
  int bid = blockIdx.x;
  int t = threadIdx.x;
  if (bid < 4096){
    // RMSNorm row bid + cast to bf16
    int row = bid;
    float4 v = ((const float4*)(x + (size_t)row * DIM_))[t];
    float ss = v.x*v.x + v.y*v.y + v.z*v.z + v.w*v.w;
#pragma unroll
    for (int m = 1; m < 64; m <<= 1) ss += __shfl_xor(ss, m, 64);
    float* red = &ls[0][0];
    if ((t & 63) == 0) red[t >> 6] = ss;
    __syncthreads();
    float tot = red[0] + red[1] + red[2] + red[3];
    float r = rsqrtf(tot * (1.0f / DIM_) + 1.1920929e-07f);
    float4 wv = ((const float4*)norm_w)[t];
    union { u16 u[4]; uint2 v2; } o;
    o.u[0] = f2bf(v.x * r * wv.x);
    o.u[1] = f2bf(v.y * r * wv.y);
    o.u[2] = f2bf(v.z * r * wv.z);
    o.u[3] = f2bf(v.w * r * wv.w);
    ((uint2*)(xn + (size_t)row * DIM_))[t] = o.v2;
  } else if (bid < 4864){
    // w_qkv [1024][3072] -> wqkvT [3072][1024]
    int idx = bid - 4096;
    tcast_body(w_qkv, wqkvT, DIM_, NQKV_, (idx % 48) * 64, (idx / 48) * 64, t, ls);
  } else if (bid < 5120){
    // w_out [1024][1024] -> woutT [1024][1024]
    int idx = bid - 4864;
    tcast_body(w_out, woutT, DIM_, DIM_, (idx & 15) * 64, (idx >> 4) * 64, t, ls);
  } else {
    int tid = (bid - 5120) * 256 + t;          // 65536 = N_*32
    int n = tid >> 5, i = tid & 31;
    float inv = powf(10000.0f, -(float)(2 * i) * (1.0f / 64.0f));
    float a = (float)n * inv;
    cs[tid] = make_float2(cosf(a), sinf(a));
  }
}

// ---------------- GEMM1: 128x192 tile, BK=64, counted-vmcnt, 512 thr, grid 512 ----------------
// C[4096,3072] = xn @ wqkvT^T. 8 waves (2m x 4n), per-wave 64x48 out, acc[4][3].
// 16 waves/CU (2 blocks x 8) = 4 waves/SIMD for latency hiding. Staging 5 loads/wave.
// Epilogue: cols<2048 -> fused interleaved RoPE (q scaled 0.125*log2e) -> bf16 qkv2;
// cols>=2048 -> fp32 orig_v + bf16 vT2 tiled.
__global__ __launch_bounds__(512, 2) void k_gemm1(const u16* __restrict__ A,
                                                  const u16* __restrict__ Bt,
                                                  u16* __restrict__ outb,
                                                  float* __restrict__ outf,
                                                  u16* __restrict__ vt2,
                                                  const float2* __restrict__ cs){
  __shared__ u16 As[2][8192];    // [128 m][64 k] per buf, chunk-XOR swizzle (32KB)
  __shared__ u16 Bs[2][12288];   // [192 n][64 k] per buf (48KB)
  const int K = 1024, KT = 16;

  int xcd = blockIdx.x & 7, c = blockIdx.x >> 3;       // c in 0..63
  int m0 = ((xcd >> 1) * 8 + (c >> 3)) << 7;           // m-panel 0..31 (128 rows)
  int n0 = ((xcd & 1) * 8 + (c & 7)) * 192;            // n-panel 0..15 (192 cols)

  int t = threadIdx.x, wv = t >> 6, lane = t & 63, l15 = lane & 15, g = lane >> 4;
  int wm = wv >> 2, wn = wv & 3;                       // 2m x 4n wave grid

  auto STAGE = [&](int buf, int kt){
    int k0 = kt << 6;
#pragma unroll
    for (int i = 0; i < 2; i++){           // A: 128 rows x 64 k = 16KB (2 loads/wave)
      int cc = (i * 8 + wv) * 64 + lane;
      int m = cc >> 3, pos = cc & 7;
      GLL16(A + (size_t)(m0 + m) * K + k0 + ((pos ^ (m & 7)) << 3), &As[buf][(i * 8 + wv) * 512]);
    }
#pragma unroll
    for (int i = 0; i < 3; i++){           // B: 192 rows x 64 k = 24KB (3 loads/wave)
      int cc = (i * 8 + wv) * 64 + lane;
      int n = cc >> 3, pos = cc & 7;
      GLL16(Bt + (size_t)(n0 + n) * K + k0 + ((pos ^ (n & 7)) << 3), &Bs[buf][(i * 8 + wv) * 512]);
    }
  };

  f32x4 acc[4][3] = {};
  STAGE(0, 0);
  STAGE(1, 1);

  for (int kt = 0; kt < KT; kt++){
    if (kt < KT - 1) asm volatile("s_waitcnt vmcnt(5)" ::: "memory");
    else             asm volatile("s_waitcnt vmcnt(0)" ::: "memory");
    SCHEDB; BARRIER; SCHEDB;
    const u16* Asc = &As[kt & 1][0];
    const u16* Bsc = &Bs[kt & 1][0];
#pragma unroll
    for (int h = 0; h < 2; h++){
      short8 af[4], bfr[3];
#pragma unroll
      for (int mi = 0; mi < 4; mi++){
        int m = wm * 64 + mi * 16 + l15;
        af[mi] = *(const short8*)(Asc + m * 64 + (((h * 4 + g) ^ (m & 7)) << 3));
      }
#pragma unroll
      for (int ni = 0; ni < 3; ni++){
        int n = wn * 48 + ni * 16 + l15;
        bfr[ni] = *(const short8*)(Bsc + n * 64 + (((h * 4 + g) ^ (n & 7)) << 3));
      }
      __builtin_amdgcn_s_setprio(1);
#pragma unroll
      for (int mi = 0; mi < 4; mi++)
#pragma unroll
        for (int ni = 0; ni < 3; ni++)
          acc[mi][ni] = __builtin_amdgcn_mfma_f32_16x16x32_bf16(af[mi], bfr[ni], acc[mi][ni], 0, 0, 0);
      __builtin_amdgcn_s_setprio(0);
    }
    asm volatile("s_waitcnt lgkmcnt(0)" ::: "memory");
    SCHEDB; BARRIER; SCHEDB;
    if (kt + 2 < KT) STAGE(kt & 1, kt + 2);
  }

#pragma unroll
  for (int mi = 0; mi < 4; mi++){
#pragma unroll
    for (int ni = 0; ni < 3; ni++){
      int col = n0 + wn * 48 + ni * 16 + l15;
#pragma unroll
      for (int r = 0; r < 4; r++){
        int row = m0 + wm * 64 + mi * 16 + g * 4 + r;
        float val = acc[mi][ni][r];
        if (col < NQK_){
          // fused interleaved RoPE: partner element lives in adjacent lane
          int n = row & (N_ - 1);
          int dpair = (col & 63) >> 1;
          float2 cv = cs[(size_t)n * 32 + dpair];
          float partner = __shfl_xor(val, 1, 64);
          float y = (l15 & 1) ? (val * cv.x + partner * cv.y)
                              : (val * cv.x - partner * cv.y);
          if (col < DIM_) y *= 0.18033688f;   // (1/8)*log2(e): log2-domain scores
          outb[(size_t)row * NQK_ + col] = f2bf(y);
        } else {
          int hh = (col - 2 * DIM_) >> 6, d = col & 63;
          int b = row >> 11, n = row & (N_ - 1);
          outf[((size_t)((b * H_ + hh) * N_ + n) << 6) + d] = val;
          // vT2 tiled: [bh][n>>5][d][n&31]
          vt2[((size_t)((b * H_ + hh) * 64 + (n >> 5)) * 64 + d) * 32 + (n & 31)] = f2bf(val);
        }
      }
    }
  }
}

// ---------------- GEMM2: 128x128 tile, BK=128, counted-vmcnt, grid 256 ----------------
__global__ __launch_bounds__(256) void k_gemm2(const u16* __restrict__ A,
                                               const u16* __restrict__ Bt,
                                               float* __restrict__ outf){
  __shared__ u16 As[2][16384];   // [128 m][128 k] per buf (32KB each)
  __shared__ u16 Bs[2][16384];   // [128 n][128 k] per buf (32KB each)
  const int K = 1024, KT = 8, N = 1024;

  int xcd = blockIdx.x & 7, c = blockIdx.x >> 3;       // c in 0..31
  int m0 = (xcd * 4 + (c >> 3)) << 7;
  int n0 = (c & 7) << 7;

  int t = threadIdx.x, wv = t >> 6, lane = t & 63, l15 = lane & 15, g = lane >> 4;
  int wm = wv >> 1, wn = wv & 1;

  auto STAGE = [&](int buf, int kt){
    int k0 = kt << 7;
#pragma unroll
    for (int i = 0; i < 8; i++){
      int s = (i * 4 + wv) * 64 + lane;        // slot 0..2047
      int m = s >> 4;                          // row
      int lc = (s & 15) ^ (m & 15);            // logical chunk
      GLL16(A + (size_t)(m0 + m) * K + k0 + (lc << 3), &As[buf][(i * 4 + wv) * 512]);
    }
#pragma unroll
    for (int i = 0; i < 8; i++){
      int s = (i * 4 + wv) * 64 + lane;
      int n = s >> 4;
      int lc = (s & 15) ^ (n & 15);
      GLL16(Bt + (size_t)(n0 + n) * K + k0 + (lc << 3), &Bs[buf][(i * 4 + wv) * 512]);
    }
  };

  f32x4 acc[4][4] = {};
  STAGE(0, 0);
  STAGE(1, 1);

  for (int kt = 0; kt < KT; kt++){
    if (kt < KT - 1) asm volatile("s_waitcnt vmcnt(16)" ::: "memory");
    else             asm volatile("s_waitcnt vmcnt(0)" ::: "memory");
    SCHEDB; BARRIER; SCHEDB;
    const u16* Asc = &As[kt & 1][0];
    const u16* Bsc = &Bs[kt & 1][0];
#pragma unroll
    for (int h = 0; h < 4; h++){               // 4 k-steps of 32
      short8 af[4], bfr[4];
#pragma unroll
      for (int mi = 0; mi < 4; mi++){
        int m = wm * 64 + mi * 16 + l15;
        af[mi] = *(const short8*)(Asc + m * 128 + (((h * 4 + g) ^ (m & 15)) << 3));
      }
#pragma unroll
      for (int ni = 0; ni < 4; ni++){
        int n = wn * 64 + ni * 16 + l15;
        bfr[ni] = *(const short8*)(Bsc + n * 128 + (((h * 4 + g) ^ (n & 15)) << 3));
      }
      __builtin_amdgcn_s_setprio(1);
#pragma unroll
      for (int mi = 0; mi < 4; mi++)
#pragma unroll
        for (int ni = 0; ni < 4; ni++)
          acc[mi][ni] = __builtin_amdgcn_mfma_f32_16x16x32_bf16(af[mi], bfr[ni], acc[mi][ni], 0, 0, 0);
      __builtin_amdgcn_s_setprio(0);
    }
    asm volatile("s_waitcnt lgkmcnt(0)" ::: "memory");
    SCHEDB; BARRIER; SCHEDB;
    if (kt + 2 < KT) STAGE(kt & 1, kt + 2);
  }

#pragma unroll
  for (int mi = 0; mi < 4; mi++){
#pragma unroll
    for (int ni = 0; ni < 4; ni++){
      int col = n0 + wn * 64 + ni * 16 + l15;
#pragma unroll
      for (int r = 0; r < 4; r++){
        int row = m0 + wm * 64 + mi * 16 + g * 4 + r;
        outf[(size_t)row * N + col] = acc[mi][ni][r];
      }
    }
  }
}

// ---------------- flash block-causal attention (R10 schedule, log2 softmax) ----------------
// Softmax denominator via MFMA against all-ones B-fragment: lacc[r] accumulates
// row-sums of bf16 P in the same register layout as oacc (no shuffles).
__global__ __launch_bounds__(512, 4) void k_attn(const u16* __restrict__ qkv2,
                                                 const u16* __restrict__ vt2,
                                                 u16* __restrict__ ao){
  __shared__ u16 Ks[2][8192];   // [kv=128][hd=64] per buf, XOR-swizzled chunks (32KB)
  __shared__ u16 Vs[8192];      // [d=64][kv=128], XOR-swizzled chunks (16KB)
  __shared__ u16 Ps[8][1024];   // per-wave P half [16q][64kv], swizzle ^((q&7)<<4) (16KB)

  int bid = blockIdx.x;
  int bh = bid & 31;                          // bid%8 stable -> same-bh on same XCD
  int idx = (bid >> 5) & 7;
  int half = bid >> 8;
  int qb = half ? idx : 15 - idx;
  int b = bh >> 4, h = bh & 15;
  int t = threadIdx.x, wv = t >> 6, lane = t & 63, l15 = lane & 15, g = lane >> 4;

  int qrow = qb * 128 + wv * 16 + l15;
  const u16* qp = qkv2 + (size_t)(b * N_ + qrow) * NQK_ + h * 64 + g * 8;
  short8 qfa = *(const short8*)qp;        // roped + (1/8)*log2e-scaled by gemm1
  short8 qfb = *(const short8*)(qp + 32);

  union { u16 u[8]; short8 s; } one_;
#pragma unroll
  for (int i = 0; i < 8; i++) one_.u[i] = 0x3F80;   // bf16 1.0
  const short8 onesf = one_.s;

  char* Pw = (char*)&Ps[wv][0];
  const u16* vb_ = vt2 + (size_t)bh * 4096 * 32;   // vt2[bh][nc][d][32]

  auto STAGE_K = [&](int buf, int j) {
#pragma unroll
    for (int i = 0; i < 2; i++){
      int c = (i * 8 + wv) * 64 + lane;
      int kv = c >> 3, pos = c & 7;
      GLL16(qkv2 + (size_t)(b * N_ + j * 128 + kv) * NQK_ + DIM_ + h * 64 + ((pos ^ (kv & 7)) << 3),
            &Ks[buf][(i * 8 + wv) * 512]);
    }
  };
  auto STAGE_V = [&](int j) {
#pragma unroll
    for (int i = 0; i < 2; i++){
      int c = (wv * 2 + i) * 64 + lane;
      int d = c >> 4;
      int lc = (c & 15) ^ (d & 7);
      GLL16(vb_ + ((size_t)((j * 4 + (lc >> 2)) * 64 + d) * 32) + ((lc & 3) << 3),
            &Vs[(wv * 2 + i) * 512]);
    }
  };

  f32x4 oacc[4] = {};
  f32x4 lacc = {};
  float m_run = -INFINITY;

  STAGE_K(0, 0);
  __syncthreads();
  int cur = 0;

  for (int j = 0; j <= qb; j++){
    STAGE_V(j);                                // issues 2 loads (oldest)
    if (j < qb) STAGE_K(cur ^ 1, j + 1);       // issues 2 more (newest)
    const u16* K = &Ks[cur][0];

    f32x4 sv[8];
    __builtin_amdgcn_s_setprio(1);
#pragma unroll
    for (int s = 0; s < 8; s++){
      int kvr = s * 16 + l15;
      short8 kf0 = *(const short8*)(K + kvr * 64 + ((g ^ (kvr & 7)) << 3));
      short8 kf1 = *(const short8*)(K + kvr * 64 + (((4 + g) ^ (kvr & 7)) << 3));
      f32x4 z = {0.f, 0.f, 0.f, 0.f};
      z = __builtin_amdgcn_mfma_f32_16x16x32_bf16(kf0, qfa, z, 0, 0, 0);
      z = __builtin_amdgcn_mfma_f32_16x16x32_bf16(kf1, qfb, z, 0, 0, 0);
      sv[s] = z;
    }
    __builtin_amdgcn_s_setprio(0);

    // online softmax in log2 domain; max via v_max3-fusable pairs (16-op chain)
    float mt = fmaxf(sv[0][0], sv[0][1]);
    mt = fmaxf(fmaxf(sv[0][2], sv[0][3]), mt);
#pragma unroll
    for (int s = 1; s < 8; s++){
      mt = fmaxf(fmaxf(sv[s][0], sv[s][1]), mt);
      mt = fmaxf(fmaxf(sv[s][2], sv[s][3]), mt);
    }
    mt = fmaxf(mt, __shfl_xor(mt, 16, 64));
    mt = fmaxf(mt, __shfl_xor(mt, 32, 64));
    if (!__all(mt <= m_run + 11.5415603f)){    // defer-max THR = 8*log2(e)
      float m_new = fmaxf(m_run, mt);
      float alpha = exp2f(m_run - m_new);
      float af4[4];
#pragma unroll
      for (int r = 0; r < 4; r++) af4[r] = __shfl(alpha, g * 4 + r, 64);
#pragma unroll
      for (int r = 0; r < 4; r++){
#pragma unroll
        for (int ni = 0; ni < 4; ni++) oacc[ni][r] *= af4[r];
        lacc[r] *= af4[r];
      }
      m_run = m_new;
    }
#pragma unroll
    for (int s = 0; s < 8; s++)
#pragma unroll
      for (int r = 0; r < 4; r++)
        sv[s][r] = exp2f(sv[s][r] - m_run);

    // V(j) landed (own oldest 2 loads); K(j+1) stays in flight through PV
    if (j < qb) asm volatile("s_waitcnt vmcnt(2)" ::: "memory");
    else        asm volatile("s_waitcnt vmcnt(0)" ::: "memory");
    SCHEDB; BARRIER; SCHEDB;

#pragma unroll
    for (int hf = 0; hf < 2; hf++){
#pragma unroll
      for (int s2 = 0; s2 < 4; s2++){
        int s = hf * 4 + s2;
        uint2 pk;
        pk.x = cvtpk(sv[s][0], sv[s][1]);
        pk.y = cvtpk(sv[s][2], sv[s][3]);
        int byte = (l15 * 128 + s2 * 32 + g * 8) ^ ((l15 & 7) << 4);
        *(uint2*)(Pw + byte) = pk;
      }
      __builtin_amdgcn_s_setprio(1);
#pragma unroll
      for (int cc2 = 0; cc2 < 2; cc2++){
        int cc = hf * 2 + cc2;
        int rb = (l15 * 128 + cc2 * 64 + g * 16) ^ ((l15 & 7) << 4);
        short8 pa = *(const short8*)(Pw + rb);
#pragma unroll
        for (int ni = 0; ni < 4; ni++){
          int d = ni * 16 + l15;
          short8 vf = *(const short8*)(Vs + d * 128 + (((cc * 4 + g) ^ (d & 7)) << 3));
          oacc[ni] = __builtin_amdgcn_mfma_f32_16x16x32_bf16(pa, vf, oacc[ni], 0, 0, 0);
        }
        lacc = __builtin_amdgcn_mfma_f32_16x16x32_bf16(pa, onesf, lacc, 0, 0, 0);
      }
      __builtin_amdgcn_s_setprio(0);
    }

    __syncthreads();   // all waves done with Vs / Ks[cur]; K(j+1) drained (flew full tile)
    cur ^= 1;
  }

#pragma unroll
  for (int ni = 0; ni < 4; ni++)
#pragma unroll
    for (int r = 0; r < 4; r++){
      size_t idxo = (size_t)(b * N_ + qb * 128 + wv * 16 + g * 4 + r) * DIM_ + h * 64 + ni * 16 + l15;
      ao[idxo] = f2bf(oacc[ni][r] / lacc[r]);
    }
}

// ---------------- launch ----------------
extern "C" void kernel_launch(void* const* d_in, const int* in_sizes, int n_in,
                              void* d_out, int out_size, void* d_ws, size_t ws_size,
                              hipStream_t stream){
  const float* x      = (const float*)d_in[0];
  const float* norm_w = (const float*)d_in[1];
  const float* w_qkv  = (const float*)d_in[2];
  const float* w_out  = (const float*)d_in[3];
  float* out0 = (float*)d_out;                      // [B,N,DIM] fp32
  float* out1 = out0 + (size_t)NR_ * DIM_;          // orig_v [B,H,N,DH] fp32

  char* ws = (char*)d_ws;
  u16* xn    = (u16*)(ws + 0);           // 8 MB (reused as attn-out after GEMM1)
  u16* wqkvT = (u16*)(ws + 8388608);     // 6 MB
  u16* woutT = (u16*)(ws + 14680064);    // 2 MB
  u16* qkv2  = (u16*)(ws + 16777216);    // 16 MB  [row][2048] roped q|k bf16
  u16* vt2   = (u16*)(ws + 33554432);    // 8 MB   [bh][64][64][32] bf16
  float2* cs = (float2*)(ws + 41943040); // 0.5 MB
  u16* ao    = xn;                       // alias: xn dead after GEMM1

  k_prep<<<5376, 256, 0, stream>>>(x, norm_w, xn, w_qkv, w_out, wqkvT, woutT, cs);
  k_gemm1<<<512, 512, 0, stream>>>(xn, wqkvT, qkv2, out1, vt2, cs);
  k_attn<<<512, 512, 0, stream>>>(qkv2, vt2, ao);
  k_gemm2<<<256, 256, 0, stream>>>(ao, woutT, out0);
}

// Round 19
// 114.970 us; speedup vs baseline: 1.1763x; 1.0154x over previous
//
#include <hip/hip_runtime.h>
#include <stdint.h>

#define B_    2
#define N_    2048
#define DIM_  1024
#define H_    16
#define DH_   64
#define NR_   4096     // B*N rows
#define NQKV_ 3072
#define NQK_  2048     // q,k columns kept in qkv2

typedef unsigned short u16;
typedef __attribute__((ext_vector_type(8))) short short8;
typedef __attribute__((ext_vector_type(4))) float f32x4;

static __device__ __forceinline__ u16 f2bf(float f){
  union { float f; uint32_t u; } x; x.f = f;
  return (u16)((x.u + 0x7fffu + ((x.u >> 16) & 1u)) >> 16);
}
static __device__ __forceinline__ float bf2f(uint32_t b){
  union { uint32_t u; float f; } x; x.u = b << 16;
  return x.f;
}
// hardware packed f32->bf16 (RNE): D = {lo: bf16(a), hi: bf16(b)}
static __device__ __forceinline__ uint32_t cvtpk(float a, float b){
  uint32_t r;
  asm("v_cvt_pk_bf16_f32 %0, %1, %2" : "=v"(r) : "v"(a), "v"(b));
  return r;
}

// global -> LDS direct copy, 16B per lane; LDS dest is wave-uniform base + lane*16
#define GLL16(gp, lp) __builtin_amdgcn_global_load_lds( \
    (const __attribute__((address_space(1))) void*)(gp), \
    (__attribute__((address_space(3))) void*)(lp), 16, 0, 0)

#define SCHEDB __builtin_amdgcn_sched_barrier(0)
#define BARRIER __builtin_amdgcn_s_barrier()

// ---------------- fused prep: RMSNorm + both weight transposes + cos/sin ----------------
static __device__ __forceinline__ void tcast_body(const float* __restrict__ src,
                                                  u16* __restrict__ dst,
                                                  int R, int C, int c0, int r0, int t,
                                                  float (*ls)[65]){
  int rr = t >> 2, q = t & 3;
  const float* s = src + (size_t)(r0 + rr) * C + c0 + q * 16;
#pragma unroll
  for (int j = 0; j < 4; j++){
    float4 v = ((const float4*)s)[j];
    ls[rr][q*16 + j*4 + 0] = v.x;
    ls[rr][q*16 + j*4 + 1] = v.y;
    ls[rr][q*16 + j*4 + 2] = v.z;
    ls[rr][q*16 + j*4 + 3] = v.w;
  }
  __syncthreads();
  int cc = t >> 2;
  union { u16 u[16]; uint4 v4[2]; } o;
#pragma unroll
  for (int i = 0; i < 16; i++) o.u[i] = f2bf(ls[q*16 + i][cc]);
  u16* d = dst + (size_t)(c0 + cc) * R + r0 + q * 16;
  ((uint4*)d)[0] = o.v4[0];
  ((uint4*)d)[1] = o.v4[1];
}

__global__ __launch_bounds__(256) void k_prep(const float* __restrict__ x,
                                              const float* __restrict__ norm_w,
                                              u16* __restrict__ xn,
                                              const float* __restrict__ w_qkv,
                                              const float* __restrict__ w_out,
                                              u16* __restrict__ wqkvT,
                                              u16* __restrict__ woutT,
                                              float2* __restrict__ cs){
  __shared__ float ls[64][65];
  int bid = blockIdx.x;
  int t = threadIdx.x;
  if (bid < 4096){
    // RMSNorm row bid + cast to bf16
    int row = bid;
    float4 v = ((const float4*)(x + (size_t)row * DIM_))[t];
    float ss = v.x*v.x + v.y*v.y + v.z*v.z + v.w*v.w;
#pragma unroll
    for (int m = 1; m < 64; m <<= 1) ss += __shfl_xor(ss, m, 64);
    float* red = &ls[0][0];
    if ((t & 63) == 0) red[t >> 6] = ss;
    __syncthreads();
    float tot = red[0] + red[1] + red[2] + red[3];
    float r = rsqrtf(tot * (1.0f / DIM_) + 1.1920929e-07f);
    float4 wv = ((const float4*)norm_w)[t];
    union { u16 u[4]; uint2 v2; } o;
    o.u[0] = f2bf(v.x * r * wv.x);
    o.u[1] = f2bf(v.y * r * wv.y);
    o.u[2] = f2bf(v.z * r * wv.z);
    o.u[3] = f2bf(v.w * r * wv.w);
    ((uint2*)(xn + (size_t)row * DIM_))[t] = o.v2;
  } else if (bid < 4864){
    // w_qkv [1024][3072] -> wqkvT [3072][1024]
    int idx = bid - 4096;
    tcast_body(w_qkv, wqkvT, DIM_, NQKV_, (idx % 48) * 64, (idx / 48) * 64, t, ls);
  } else if (bid < 5120){
    // w_out [1024][1024] -> woutT [1024][1024]
    int idx = bid - 4864;
    tcast_body(w_out, woutT, DIM_, DIM_, (idx & 15) * 64, (idx >> 4) * 64, t, ls);
  } else {
    int tid = (bid - 5120) * 256 + t;          // 65536 = N_*32
    int n = tid >> 5, i = tid & 31;
    float inv = powf(10000.0f, -(float)(2 * i) * (1.0f / 64.0f));
    float a = (float)n * inv;
    cs[tid] = make_float2(cosf(a), sinf(a));
  }
}

// ---------------- GEMM1: 128x192 tile, BK=64, counted-vmcnt, 512 thr, grid 512 ----------------
// C[4096,3072] = xn @ wqkvT^T. 8 waves (2m x 4n), per-wave 64x48 out, acc[4][3].
// Epilogue: cols<2048 -> fused interleaved RoPE (q scaled 0.125*log2e) -> bf16 qkv2;
// cols>=2048 -> fp32 orig_v + bf16 vT2 tiled.
__global__ __launch_bounds__(512, 2) void k_gemm1(const u16* __restrict__ A,
                                                  const u16* __restrict__ Bt,
                                                  u16* __restrict__ outb,
                                                  float* __restrict__ outf,
                                                  u16* __restrict__ vt2,
                                                  const float2* __restrict__ cs){
  __shared__ u16 As[2][8192];    // [128 m][64 k] per buf, chunk-XOR swizzle (32KB)
  __shared__ u16 Bs[2][12288];   // [192 n][64 k] per buf (48KB)
  const int K = 1024, KT = 16;

  int xcd = blockIdx.x & 7, c = blockIdx.x >> 3;       // c in 0..63
  int m0 = ((xcd >> 1) * 8 + (c >> 3)) << 7;           // m-panel 0..31 (128 rows)
  int n0 = ((xcd & 1) * 8 + (c & 7)) * 192;            // n-panel 0..15 (192 cols)

  int t = threadIdx.x, wv = t >> 6, lane = t & 63, l15 = lane & 15, g = lane >> 4;
  int wm = wv >> 2, wn = wv & 3;                       // 2m x 4n wave grid

  auto STAGE = [&](int buf, int kt){
    int k0 = kt << 6;
#pragma unroll
    for (int i = 0; i < 2; i++){           // A: 128 rows x 64 k = 16KB (2 loads/wave)
      int cc = (i * 8 + wv) * 64 + lane;
      int m = cc >> 3, pos = cc & 7;
      GLL16(A + (size_t)(m0 + m) * K + k0 + ((pos ^ (m & 7)) << 3), &As[buf][(i * 8 + wv) * 512]);
    }
#pragma unroll
    for (int i = 0; i < 3; i++){           // B: 192 rows x 64 k = 24KB (3 loads/wave)
      int cc = (i * 8 + wv) * 64 + lane;
      int n = cc >> 3, pos = cc & 7;
      GLL16(Bt + (size_t)(n0 + n) * K + k0 + ((pos ^ (n & 7)) << 3), &Bs[buf][(i * 8 + wv) * 512]);
    }
  };

  f32x4 acc[4][3] = {};
  STAGE(0, 0);
  STAGE(1, 1);

  for (int kt = 0; kt < KT; kt++){
    if (kt < KT - 1) asm volatile("s_waitcnt vmcnt(5)" ::: "memory");
    else             asm volatile("s_waitcnt vmcnt(0)" ::: "memory");
    SCHEDB; BARRIER; SCHEDB;
    const u16* Asc = &As[kt & 1][0];
    const u16* Bsc = &Bs[kt & 1][0];
#pragma unroll
    for (int h = 0; h < 2; h++){
      short8 af[4], bfr[3];
#pragma unroll
      for (int mi = 0; mi < 4; mi++){
        int m = wm * 64 + mi * 16 + l15;
        af[mi] = *(const short8*)(Asc + m * 64 + (((h * 4 + g) ^ (m & 7)) << 3));
      }
#pragma unroll
      for (int ni = 0; ni < 3; ni++){
        int n = wn * 48 + ni * 16 + l15;
        bfr[ni] = *(const short8*)(Bsc + n * 64 + (((h * 4 + g) ^ (n & 7)) << 3));
      }
      __builtin_amdgcn_s_setprio(1);
#pragma unroll
      for (int mi = 0; mi < 4; mi++)
#pragma unroll
        for (int ni = 0; ni < 3; ni++)
          acc[mi][ni] = __builtin_amdgcn_mfma_f32_16x16x32_bf16(af[mi], bfr[ni], acc[mi][ni], 0, 0, 0);
      __builtin_amdgcn_s_setprio(0);
    }
    asm volatile("s_waitcnt lgkmcnt(0)" ::: "memory");
    SCHEDB; BARRIER; SCHEDB;
    if (kt + 2 < KT) STAGE(kt & 1, kt + 2);
  }

#pragma unroll
  for (int mi = 0; mi < 4; mi++){
#pragma unroll
    for (int ni = 0; ni < 3; ni++){
      int col = n0 + wn * 48 + ni * 16 + l15;
#pragma unroll
      for (int r = 0; r < 4; r++){
        int row = m0 + wm * 64 + mi * 16 + g * 4 + r;
        float val = acc[mi][ni][r];
        if (col < NQK_){
          // fused interleaved RoPE: partner element lives in adjacent lane
          int n = row & (N_ - 1);
          int dpair = (col & 63) >> 1;
          float2 cv = cs[(size_t)n * 32 + dpair];
          float partner = __shfl_xor(val, 1, 64);
          float y = (l15 & 1) ? (val * cv.x + partner * cv.y)
                              : (val * cv.x - partner * cv.y);
          if (col < DIM_) y *= 0.18033688f;   // (1/8)*log2(e): log2-domain scores
          outb[(size_t)row * NQK_ + col] = f2bf(y);
        } else {
          int hh = (col - 2 * DIM_) >> 6, d = col & 63;
          int b = row >> 11, n = row & (N_ - 1);
          outf[((size_t)((b * H_ + hh) * N_ + n) << 6) + d] = val;
          // vT2 tiled: [bh][n>>5][d][n&31]
          vt2[((size_t)((b * H_ + hh) * 64 + (n >> 5)) * 64 + d) * 32 + (n & 31)] = f2bf(val);
        }
      }
    }
  }
}

// ---------------- GEMM2: 128x128 tile, BK=128, counted-vmcnt, 512 thr, grid 256 ----------------
// out0[4096,1024] fp32 = ao @ woutT^T. 8 waves (2m x 4n), per-wave 64x32, acc[4][2].
// 1 block/CU (grid+LDS limited) but 8 waves = 2 waves/SIMD (vs 1 at 256 thr).
__global__ __launch_bounds__(512) void k_gemm2(const u16* __restrict__ A,
                                               const u16* __restrict__ Bt,
                                               float* __restrict__ outf){
  __shared__ u16 As[2][16384];   // [128 m][128 k] per buf (32KB each)
  __shared__ u16 Bs[2][16384];   // [128 n][128 k] per buf (32KB each)
  const int K = 1024, KT = 8, N = 1024;

  int xcd = blockIdx.x & 7, c = blockIdx.x >> 3;       // c in 0..31
  int m0 = (xcd * 4 + (c >> 3)) << 7;
  int n0 = (c & 7) << 7;

  int t = threadIdx.x, wv = t >> 6, lane = t & 63, l15 = lane & 15, g = lane >> 4;
  int wm = wv >> 2, wn = wv & 3;                       // 2m x 4n wave grid

  // stage one 128x128 bf16 tile (32KB): 4 gload_lds per wave per matrix.
  auto STAGE = [&](int buf, int kt){
    int k0 = kt << 7;
#pragma unroll
    for (int i = 0; i < 4; i++){
      int s = (i * 8 + wv) * 64 + lane;        // slot 0..2047
      int m = s >> 4;                          // row
      int lc = (s & 15) ^ (m & 15);            // logical chunk
      GLL16(A + (size_t)(m0 + m) * K + k0 + (lc << 3), &As[buf][(i * 8 + wv) * 512]);
    }
#pragma unroll
    for (int i = 0; i < 4; i++){
      int s = (i * 8 + wv) * 64 + lane;
      int n = s >> 4;
      int lc = (s & 15) ^ (n & 15);
      GLL16(Bt + (size_t)(n0 + n) * K + k0 + (lc << 3), &Bs[buf][(i * 8 + wv) * 512]);
    }
  };

  f32x4 acc[4][2] = {};
  STAGE(0, 0);
  STAGE(1, 1);

  for (int kt = 0; kt < KT; kt++){
    if (kt < KT - 1) asm volatile("s_waitcnt vmcnt(8)" ::: "memory");
    else             asm volatile("s_waitcnt vmcnt(0)" ::: "memory");
    SCHEDB; BARRIER; SCHEDB;
    const u16* Asc = &As[kt & 1][0];
    const u16* Bsc = &Bs[kt & 1][0];
#pragma unroll
    for (int h = 0; h < 4; h++){               // 4 k-steps of 32
      short8 af[4], bfr[2];
#pragma unroll
      for (int mi = 0; mi < 4; mi++){
        int m = wm * 64 + mi * 16 + l15;
        af[mi] = *(const short8*)(Asc + m * 128 + (((h * 4 + g) ^ (m & 15)) << 3));
      }
#pragma unroll
      for (int ni = 0; ni < 2; ni++){
        int n = wn * 32 + ni * 16 + l15;
        bfr[ni] = *(const short8*)(Bsc + n * 128 + (((h * 4 + g) ^ (n & 15)) << 3));
      }
      __builtin_amdgcn_s_setprio(1);
#pragma unroll
      for (int mi = 0; mi < 4; mi++)
#pragma unroll
        for (int ni = 0; ni < 2; ni++)
          acc[mi][ni] = __builtin_amdgcn_mfma_f32_16x16x32_bf16(af[mi], bfr[ni], acc[mi][ni], 0, 0, 0);
      __builtin_amdgcn_s_setprio(0);
    }
    asm volatile("s_waitcnt lgkmcnt(0)" ::: "memory");
    SCHEDB; BARRIER; SCHEDB;
    if (kt + 2 < KT) STAGE(kt & 1, kt + 2);
  }

#pragma unroll
  for (int mi = 0; mi < 4; mi++){
#pragma unroll
    for (int ni = 0; ni < 2; ni++){
      int col = n0 + wn * 32 + ni * 16 + l15;
#pragma unroll
      for (int r = 0; r < 4; r++){
        int row = m0 + wm * 64 + mi * 16 + g * 4 + r;
        outf[(size_t)row * N + col] = acc[mi][ni][r];
      }
    }
  }
}

// ---------------- flash block-causal attention (R10 schedule, log2 softmax) ----------------
// Softmax denominator via MFMA against all-ones B-fragment: lacc[r] accumulates
// row-sums of bf16 P in the same register layout as oacc (no shuffles).
__global__ __launch_bounds__(512, 4) void k_attn(const u16* __restrict__ qkv2,
                                                 const u16* __restrict__ vt2,
                                                 u16* __restrict__ ao){
  __shared__ u16 Ks[2][8192];   // [kv=128][hd=64] per buf, XOR-swizzled chunks (32KB)
  __shared__ u16 Vs[8192];      // [d=64][kv=128], XOR-swizzled chunks (16KB)
  __shared__ u16 Ps[8][1024];   // per-wave P half [16q][64kv], swizzle ^((q&7)<<4) (16KB)

  int bid = blockIdx.x;
  int bh = bid & 31;                          // bid%8 stable -> same-bh on same XCD
  int idx = (bid >> 5) & 7;
  int half = bid >> 8;
  int qb = half ? idx : 15 - idx;
  int b = bh >> 4, h = bh & 15;
  int t = threadIdx.x, wv = t >> 6, lane = t & 63, l15 = lane & 15, g = lane >> 4;

  int qrow = qb * 128 + wv * 16 + l15;
  const u16* qp = qkv2 + (size_t)(b * N_ + qrow) * NQK_ + h * 64 + g * 8;
  short8 qfa = *(const short8*)qp;        // roped + (1/8)*log2e-scaled by gemm1
  short8 qfb = *(const short8*)(qp + 32);

  union { u16 u[8]; short8 s; } one_;
#pragma unroll
  for (int i = 0; i < 8; i++) one_.u[i] = 0x3F80;   // bf16 1.0
  const short8 onesf = one_.s;

  char* Pw = (char*)&Ps[wv][0];
  const u16* vb_ = vt2 + (size_t)bh * 4096 * 32;   // vt2[bh][nc][d][32]

  auto STAGE_K = [&](int buf, int j) {
#pragma unroll
    for (int i = 0; i < 2; i++){
      int c = (i * 8 + wv) * 64 + lane;
      int kv = c >> 3, pos = c & 7;
      GLL16(qkv2 + (size_t)(b * N_ + j * 128 + kv) * NQK_ + DIM_ + h * 64 + ((pos ^ (kv & 7)) << 3),
            &Ks[buf][(i * 8 + wv) * 512]);
    }
  };
  auto STAGE_V = [&](int j) {
#pragma unroll
    for (int i = 0; i < 2; i++){
      int c = (wv * 2 + i) * 64 + lane;
      int d = c >> 4;
      int lc = (c & 15) ^ (d & 7);
      GLL16(vb_ + ((size_t)((j * 4 + (lc >> 2)) * 64 + d) * 32) + ((lc & 3) << 3),
            &Vs[(wv * 2 + i) * 512]);
    }
  };

  f32x4 oacc[4] = {};
  f32x4 lacc = {};
  float m_run = -INFINITY;

  STAGE_K(0, 0);
  __syncthreads();
  int cur = 0;

  for (int j = 0; j <= qb; j++){
    STAGE_V(j);                                // issues 2 loads (oldest)
    if (j < qb) STAGE_K(cur ^ 1, j + 1);       // issues 2 more (newest)
    const u16* K = &Ks[cur][0];

    f32x4 sv[8];
    __builtin_amdgcn_s_setprio(1);
#pragma unroll
    for (int s = 0; s < 8; s++){
      int kvr = s * 16 + l15;
      short8 kf0 = *(const short8*)(K + kvr * 64 + ((g ^ (kvr & 7)) << 3));
      short8 kf1 = *(const short8*)(K + kvr * 64 + (((4 + g) ^ (kvr & 7)) << 3));
      f32x4 z = {0.f, 0.f, 0.f, 0.f};
      z = __builtin_amdgcn_mfma_f32_16x16x32_bf16(kf0, qfa, z, 0, 0, 0);
      z = __builtin_amdgcn_mfma_f32_16x16x32_bf16(kf1, qfb, z, 0, 0, 0);
      sv[s] = z;
    }
    __builtin_amdgcn_s_setprio(0);

    // online softmax in log2 domain; max via v_max3-fusable pairs (16-op chain)
    float mt = fmaxf(sv[0][0], sv[0][1]);
    mt = fmaxf(fmaxf(sv[0][2], sv[0][3]), mt);
#pragma unroll
    for (int s = 1; s < 8; s++){
      mt = fmaxf(fmaxf(sv[s][0], sv[s][1]), mt);
      mt = fmaxf(fmaxf(sv[s][2], sv[s][3]), mt);
    }
    mt = fmaxf(mt, __shfl_xor(mt, 16, 64));
    mt = fmaxf(mt, __shfl_xor(mt, 32, 64));
    if (!__all(mt <= m_run + 11.5415603f)){    // defer-max THR = 8*log2(e)
      float m_new = fmaxf(m_run, mt);
      float alpha = exp2f(m_run - m_new);
      float af4[4];
#pragma unroll
      for (int r = 0; r < 4; r++) af4[r] = __shfl(alpha, g * 4 + r, 64);
#pragma unroll
      for (int r = 0; r < 4; r++){
#pragma unroll
        for (int ni = 0; ni < 4; ni++) oacc[ni][r] *= af4[r];
        lacc[r] *= af4[r];
      }
      m_run = m_new;
    }
#pragma unroll
    for (int s = 0; s < 8; s++)
#pragma unroll
      for (int r = 0; r < 4; r++)
        sv[s][r] = exp2f(sv[s][r] - m_run);

    // V(j) landed (own oldest 2 loads); K(j+1) stays in flight through PV
    if (j < qb) asm volatile("s_waitcnt vmcnt(2)" ::: "memory");
    else        asm volatile("s_waitcnt vmcnt(0)" ::: "memory");
    SCHEDB; BARRIER; SCHEDB;

#pragma unroll
    for (int hf = 0; hf < 2; hf++){
#pragma unroll
      for (int s2 = 0; s2 < 4; s2++){
        int s = hf * 4 + s2;
        uint2 pk;
        pk.x = cvtpk(sv[s][0], sv[s][1]);
        pk.y = cvtpk(sv[s][2], sv[s][3]);
        int byte = (l15 * 128 + s2 * 32 + g * 8) ^ ((l15 & 7) << 4);
        *(uint2*)(Pw + byte) = pk;
      }
      __builtin_amdgcn_s_setprio(1);
#pragma unroll
      for (int cc2 = 0; cc2 < 2; cc2++){
        int cc = hf * 2 + cc2;
        int rb = (l15 * 128 + cc2 * 64 + g * 16) ^ ((l15 & 7) << 4);
        short8 pa = *(const short8*)(Pw + rb);
#pragma unroll
        for (int ni = 0; ni < 4; ni++){
          int d = ni * 16 + l15;
          short8 vf = *(const short8*)(Vs + d * 128 + (((cc * 4 + g) ^ (d & 7)) << 3));
          oacc[ni] = __builtin_amdgcn_mfma_f32_16x16x32_bf16(pa, vf, oacc[ni], 0, 0, 0);
        }
        lacc = __builtin_amdgcn_mfma_f32_16x16x32_bf16(pa, onesf, lacc, 0, 0, 0);
      }
      __builtin_amdgcn_s_setprio(0);
    }

    __syncthreads();   // all waves done with Vs / Ks[cur]; K(j+1) drained (flew full tile)
    cur ^= 1;
  }

#pragma unroll
  for (int ni = 0; ni < 4; ni++)
#pragma unroll
    for (int r = 0; r < 4; r++){
      size_t idxo = (size_t)(b * N_ + qb * 128 + wv * 16 + g * 4 + r) * DIM_ + h * 64 + ni * 16 + l15;
      ao[idxo] = f2bf(oacc[ni][r] / lacc[r]);
    }
}

// ---------------- launch ----------------
extern "C" void kernel_launch(void* const* d_in, const int* in_sizes, int n_in,
                              void* d_out, int out_size, void* d_ws, size_t ws_size,
                              hipStream_t stream){
  const float* x      = (const float*)d_in[0];
  const float* norm_w = (const float*)d_in[1];
  const float* w_qkv  = (const float*)d_in[2];
  const float* w_out  = (const float*)d_in[3];
  float* out0 = (float*)d_out;                      // [B,N,DIM] fp32
  float* out1 = out0 + (size_t)NR_ * DIM_;          // orig_v [B,H,N,DH] fp32

  char* ws = (char*)d_ws;
  u16* xn    = (u16*)(ws + 0);           // 8 MB (reused as attn-out after GEMM1)
  u16* wqkvT = (u16*)(ws + 8388608);     // 6 MB
  u16* woutT = (u16*)(ws + 14680064);    // 2 MB
  u16* qkv2  = (u16*)(ws + 16777216);    // 16 MB  [row][2048] roped q|k bf16
  u16* vt2   = (u16*)(ws + 33554432);    // 8 MB   [bh][64][64][32] bf16
  float2* cs = (float2*)(ws + 41943040); // 0.5 MB
  u16* ao    = xn;                       // alias: xn dead after GEMM1

  k_prep<<<5376, 256, 0, stream>>>(x, norm_w, xn, w_qkv, w_out, wqkvT, woutT, cs);
  k_gemm1<<<512, 512, 0, stream>>>(xn, wqkvT, qkv2, out1, vt2, cs);
  k_attn<<<512, 512, 0, stream>>>(qkv2, vt2, ao);
  k_gemm2<<<256, 512, 0, stream>>>(ao, woutT, out0);
}